// Round 10
// baseline (982.477 us; speedup 1.0000x reference)
//
#include <hip/hip_runtime.h>
#include <hip/hip_bf16.h>
#include <math.h>

#define DEV_INLINE __device__ __forceinline__

typedef float f32x4 __attribute__((ext_vector_type(4)));

constexpr int B_    = 4;
constexpr int QLEN  = 512;
constexpr int KLEN  = 1024;
constexpr int DIM   = 512;
constexpr int H_MA  = 4;
constexpr int H_CA  = 2;
constexpr int CHUNK = 4;
constexpr float EPS = 1e-6f;
constexpr float INV_SCALE = 1.0f / 22.62741699796952f;  // 1/sqrt(512)

// ---------------------------------------------------------------------------
// 64x64 fp32 GEMM tile (kept for cv: per-slice N=64) — BK=16, 256 thr, 4x4
// ---------------------------------------------------------------------------

DEV_INLINE void gemm_nn_tile(const float* __restrict__ A, int lda,
                             const float* __restrict__ Bm, int ldb,
                             float* __restrict__ C, int ldc,
                             int K, const float* __restrict__ bias,
                             int bm, int bn)
{
    __shared__ float As[16][68];
    __shared__ float Bs[16][68];
    const int tid  = threadIdx.x;
    const int tm   = (tid >> 4) << 2;
    const int tn   = (tid & 15) << 2;
    const int arow = tid >> 2;
    const int acol = (tid & 3) << 2;
    const int brow = tid >> 4;
    const int bcol = (tid & 15) << 2;
    float acc[4][4] = {};

    for (int k0 = 0; k0 < K; k0 += 16) {
        const float4 av = *(const float4*)(A + (size_t)(bm + arow) * lda + k0 + acol);
        const float4 bv = *(const float4*)(Bm + (size_t)(k0 + brow) * ldb + bn + bcol);
        __syncthreads();
        As[acol + 0][arow] = av.x;
        As[acol + 1][arow] = av.y;
        As[acol + 2][arow] = av.z;
        As[acol + 3][arow] = av.w;
        *(float4*)(&Bs[brow][bcol]) = bv;
        __syncthreads();
#pragma unroll
        for (int kk = 0; kk < 16; ++kk) {
            const float4 a = *(const float4*)&As[kk][tm];
            const float4 b = *(const float4*)&Bs[kk][tn];
            const float ar[4] = {a.x, a.y, a.z, a.w};
            const float br[4] = {b.x, b.y, b.z, b.w};
#pragma unroll
            for (int i = 0; i < 4; ++i)
#pragma unroll
                for (int j = 0; j < 4; ++j)
                    acc[i][j] = fmaf(ar[i], br[j], acc[i][j]);
        }
    }
#pragma unroll
    for (int i = 0; i < 4; ++i) {
        float4 o;
        float* op = (float*)&o;
#pragma unroll
        for (int j = 0; j < 4; ++j)
            op[j] = acc[i][j] + (bias ? bias[bn + tn + j] : 0.0f);
        *(float4*)(C + (size_t)(bm + tm + i) * ldc + bn + tn) = o;
    }
}

// ---------------------------------------------------------------------------
// 128x128 fp32 GEMM tiles — BK=8, 256 threads, 8x8 acc/thread (split halves).
// Per kk: 4 ds_read_b128 feed 64 FMAs (16:1). LDS reads conflict-free:
// A reads broadcast across 16 lanes; B reads 2-way (free).
// ---------------------------------------------------------------------------

DEV_INLINE void g128_compute(const float (*As)[128], const float (*Bs)[128],
                             int ty4, int tx4, float (&acc)[8][8])
{
#pragma unroll
    for (int kk = 0; kk < 8; ++kk) {
        const f32x4 a0 = *(const f32x4*)&As[kk][ty4];
        const f32x4 a1 = *(const f32x4*)&As[kk][ty4 + 64];
        const f32x4 b0 = *(const f32x4*)&Bs[kk][tx4];
        const f32x4 b1 = *(const f32x4*)&Bs[kk][tx4 + 64];
#pragma unroll
        for (int i = 0; i < 4; ++i)
#pragma unroll
            for (int j = 0; j < 4; ++j) {
                acc[i][j]         = fmaf(a0[i], b0[j], acc[i][j]);
                acc[i][j + 4]     = fmaf(a0[i], b1[j], acc[i][j + 4]);
                acc[i + 4][j]     = fmaf(a1[i], b0[j], acc[i + 4][j]);
                acc[i + 4][j + 4] = fmaf(a1[i], b1[j], acc[i + 4][j + 4]);
            }
    }
}

// C[bm..+128, bn..+128] = A[M,K] @ B[K,N] + bias (row-major)
DEV_INLINE void gemm128_nn_tile(const float* __restrict__ A, int lda,
                                const float* __restrict__ Bm, int ldb,
                                float* __restrict__ C, int ldc,
                                int K, const float* __restrict__ bias,
                                int bm, int bn)
{
    __shared__ float As[8][128];
    __shared__ float Bs[8][128];
    const int tid = threadIdx.x;
    const int tx4 = (tid & 15) << 2;
    const int ty4 = ((tid >> 4) & 3) << 2;   // wave-local ty in 0..3 -> *4
    const int tyq = (tid >> 6);              // which wave: rows offset 0/16/32/48
    const int ry  = tyq * 16 + ty4;          // 0..60 step 4 (16 row-groups)
    const int arow = tid >> 1;               // 0..127
    const int ac   = (tid & 1) << 2;         // 0,4
    const int brow = tid >> 5;               // 0..7
    const int bc   = (tid & 31) << 2;        // 0..124
    float acc[8][8] = {};

    for (int k0 = 0; k0 < K; k0 += 8) {
        const f32x4 av = *(const f32x4*)(A + (size_t)(bm + arow) * lda + k0 + ac);
        const f32x4 bv = *(const f32x4*)(Bm + (size_t)(k0 + brow) * ldb + bn + bc);
        __syncthreads();
        As[ac + 0][arow] = av[0];
        As[ac + 1][arow] = av[1];
        As[ac + 2][arow] = av[2];
        As[ac + 3][arow] = av[3];
        *(f32x4*)&Bs[brow][bc] = bv;
        __syncthreads();
        g128_compute(As, Bs, ry, tx4, acc);
    }
#pragma unroll
    for (int ih = 0; ih < 2; ++ih)
#pragma unroll
        for (int i = 0; i < 4; ++i) {
            const int r = bm + ih * 64 + ry + i;
#pragma unroll
            for (int jh = 0; jh < 2; ++jh) {
                const int c = bn + jh * 64 + tx4;
                f32x4 o;
#pragma unroll
                for (int j = 0; j < 4; ++j)
                    o[j] = acc[ih * 4 + i][jh * 4 + j] + (bias ? bias[c + j] : 0.0f);
                *(f32x4*)(C + (size_t)r * ldc + c) = o;
            }
        }
}

// C[bm..+128, bn..+128] = (A[M,K] @ B[N,K]^T) * scale + addv (k-inner operands)
DEV_INLINE void gemm128_nt_tile(const float* __restrict__ A, int lda,
                                const float* __restrict__ Bm, int ldb,
                                float* __restrict__ C, int ldc,
                                int K, float scale, float addv,
                                int bm, int bn)
{
    __shared__ float As[8][128];
    __shared__ float Bs[8][128];
    const int tid = threadIdx.x;
    const int tx4 = (tid & 15) << 2;
    const int ty4 = ((tid >> 4) & 3) << 2;
    const int tyq = (tid >> 6);
    const int ry  = tyq * 16 + ty4;
    const int row = tid >> 1;               // 0..127
    const int kc  = (tid & 1) << 2;         // 0,4
    float acc[8][8] = {};

    for (int k0 = 0; k0 < K; k0 += 8) {
        const f32x4 av = *(const f32x4*)(A + (size_t)(bm + row) * lda + k0 + kc);
        const f32x4 bv = *(const f32x4*)(Bm + (size_t)(bn + row) * ldb + k0 + kc);
        __syncthreads();
        As[kc + 0][row] = av[0];
        As[kc + 1][row] = av[1];
        As[kc + 2][row] = av[2];
        As[kc + 3][row] = av[3];
        Bs[kc + 0][row] = bv[0];
        Bs[kc + 1][row] = bv[1];
        Bs[kc + 2][row] = bv[2];
        Bs[kc + 3][row] = bv[3];
        __syncthreads();
        g128_compute(As, Bs, ry, tx4, acc);
    }
#pragma unroll
    for (int ih = 0; ih < 2; ++ih)
#pragma unroll
        for (int i = 0; i < 4; ++i) {
            const int r = bm + ih * 64 + ry + i;
#pragma unroll
            for (int jh = 0; jh < 2; ++jh) {
                const int c = bn + jh * 64 + tx4;
                f32x4 o;
#pragma unroll
                for (int j = 0; j < 4; ++j)
                    o[j] = acc[ih * 4 + i][jh * 4 + j] * scale + addv;
                *(f32x4*)(C + (size_t)r * ldc + c) = o;
            }
        }
}

// ---------------------------------------------------------------------------

__global__ __launch_bounds__(256) void gemm128_nn_kernel(
    const float* __restrict__ A, int lda,
    const float* __restrict__ Bm, int ldb,
    float* __restrict__ C, int ldc,
    int K, const float* __restrict__ bias)
{
    gemm128_nn_tile(A, lda, Bm, ldb, C, ldc, K, bias,
                    blockIdx.x * 128, blockIdx.y * 128);
}

__global__ __launch_bounds__(256) void energy128_nt_kernel(
    const float* __restrict__ QP, const float* __restrict__ KP,
    float* __restrict__ E, int H, int HD, const float* __restrict__ radd)
{
    const int z = blockIdx.z;
    const int b = z / H;
    const int h = z - b * H;
    const float* A  = QP + (size_t)b * QLEN * DIM + h * HD;
    const float* Bm = KP + (size_t)b * KLEN * DIM + h * HD;
    float* C = E + (size_t)z * QLEN * KLEN;
    const float addv = radd ? radd[0] : 0.0f;
    gemm128_nt_tile(A, DIM, Bm, DIM, C, KLEN, HD, INV_SCALE, addv,
                    blockIdx.x * 128, blockIdx.y * 128);
}

__global__ __launch_bounds__(256) void ma_row_kernel(float* __restrict__ PCP,
                                                     float* __restrict__ ICP)
{
    const size_t row = blockIdx.x;
    float* pe = PCP + row * KLEN;
    float* pi = ICP + row * KLEN;
    const int tid = threadIdx.x;
    const int lane = tid & 63, wid = tid >> 6;

    const float4 ev = *(const float4*)(pe + tid * 4);
    float e[4] = {ev.x, ev.y, ev.z, ev.w};
    float p[4], l[4], s[4];
    float run = 0.0f;
#pragma unroll
    for (int j = 0; j < 4; ++j) {
        p[j] = 1.0f / (1.0f + expf(-e[j]));
        float om = 1.0f - p[j];
        om = fminf(fmaxf(om, EPS), 1.0f);
        l[j] = logf(om);
        run += l[j];
        s[j] = run;
    }
    const float t = run;
    float v = t;
#pragma unroll
    for (int off = 1; off < 64; off <<= 1) {
        const float u = __shfl_up(v, off);
        if (lane >= off) v += u;
    }
    __shared__ float wsum[4];
    if (lane == 63) wsum[wid] = v;
    __syncthreads();
    float base = v - t;
    for (int w = 0; w < wid; ++w) base += wsum[w];

    float4 po, io;
    float* pp = (float*)&po;
    float* ip = (float*)&io;
#pragma unroll
    for (int j = 0; j < 4; ++j) {
        const float cum = base + s[j];
        const float cp  = expf(cum - l[j]);
        pp[j] = p[j] * cp;
        ip[j] = 1.0f / fmaxf(cp, EPS);
    }
    *(float4*)(pe + tid * 4) = po;
    *(float4*)(pi + tid * 4) = io;
}

__global__ __launch_bounds__(256) void ca_row_kernel(float* __restrict__ SE,
                                                     float* __restrict__ DEN)
{
    const size_t row = blockIdx.x;
    float* ps = SE + row * KLEN;
    float* pd = DEN + row * KLEN;
    const int tid = threadIdx.x;
    const int lane = tid & 63, wid = tid >> 6;

    const float4 ev = *(const float4*)(ps + tid * 4);
    float e[4] = {ev.x, ev.y, ev.z, ev.w};
    float m = fmaxf(fmaxf(e[0], e[1]), fmaxf(e[2], e[3]));
#pragma unroll
    for (int off = 32; off >= 1; off >>= 1)
        m = fmaxf(m, __shfl_xor(m, off));
    __shared__ float wmax[4];
    if (lane == 0) wmax[wid] = m;
    __syncthreads();
    m = fmaxf(fmaxf(wmax[0], wmax[1]), fmaxf(wmax[2], wmax[3]));

    __shared__ float sh[KLEN + 3];
    if (tid < 3) sh[tid] = 0.0f;
    float se[4];
#pragma unroll
    for (int j = 0; j < 4; ++j) {
        se[j] = fmaxf(expf(e[j] - m), 1e-5f);
        sh[3 + tid * 4 + j] = se[j];
    }
    __syncthreads();
    float4 so, do_;
    float* sp = (float*)&so;
    float* dp = (float*)&do_;
#pragma unroll
    for (int j = 0; j < 4; ++j) {
        const int k = tid * 4 + j;
        sp[j] = se[j];
        dp[j] = sh[3 + k] + sh[2 + k] + sh[1 + k] + sh[k];
    }
    *(float4*)(ps + tid * 4) = so;
    *(float4*)(pd + tid * 4) = do_;
}

// ---------------------------------------------------------------------------
// alpha recurrence (ROUND-8 VERSION, verified passing incl. post-timing):
// single wave per (b,h_ma), DPP wave scan, 8-deep LDS ring via
// global_load_lds (no dest regs => no regalloc hazard), counted vmcnt.
// ---------------------------------------------------------------------------

template<int CTRL, int ROW_MASK>
DEV_INLINE float dpp_add(float x) {
    int t = __builtin_amdgcn_update_dpp(0, __float_as_int(x), CTRL, ROW_MASK, 0xf, true);
    return x + __int_as_float(t);
}

DEV_INLINE float wave64_incl_scan(float x) {
    x = dpp_add<0x111, 0xf>(x);  // row_shr:1
    x = dpp_add<0x112, 0xf>(x);  // row_shr:2
    x = dpp_add<0x114, 0xf>(x);  // row_shr:4
    x = dpp_add<0x118, 0xf>(x);  // row_shr:8
    x = dpp_add<0x142, 0xa>(x);  // row_bcast:15 -> rows 1,3
    x = dpp_add<0x143, 0xc>(x);  // row_bcast:31 -> rows 2,3
    return x;
}

typedef __attribute__((address_space(3))) void lv_t;
typedef __attribute__((address_space(1))) const void gv_t;

DEV_INLINE void dma16(const float* g, float* l) {
    __builtin_amdgcn_global_load_lds((gv_t*)g, (lv_t*)l, 16, 0, 0);
}

template<int N> DEV_INLINE void vwait() {
    asm volatile("s_waitcnt vmcnt(%0)" :: "i"(N) : "memory");
    __builtin_amdgcn_sched_barrier(0);
}

DEV_INLINE void alpha_step(const f32x4& P0, const f32x4& P1,
                           const f32x4& P2, const f32x4& P3,
                           const f32x4& I0, const f32x4& I1,
                           const f32x4& I2, const f32x4& I3,
                           float (&a)[16])
{
    float pc[16], ic[16];
    *(f32x4*)&pc[0] = P0; *(f32x4*)&pc[4] = P1;
    *(f32x4*)&pc[8] = P2; *(f32x4*)&pc[12] = P3;
    *(f32x4*)&ic[0] = I0; *(f32x4*)&ic[4] = I1;
    *(f32x4*)&ic[8] = I2; *(f32x4*)&ic[12] = I3;

    float t[16];
#pragma unroll
    for (int j = 0; j < 16; ++j) t[j] = a[j] * ic[j];

    float u1[8], u2[4];
#pragma unroll
    for (int j = 0; j < 8; ++j) u1[j] = t[2 * j] + t[2 * j + 1];
#pragma unroll
    for (int j = 0; j < 4; ++j) u2[j] = u1[2 * j] + u1[2 * j + 1];
    const float tot = (u2[0] + u2[1]) + (u2[2] + u2[3]);

    const float incl = wave64_incl_scan(tot);
    const float excl = incl - tot;

    float s = 0.0f;
#pragma unroll
    for (int j = 0; j < 16; ++j) {
        s += t[j];
        a[j] = pc[j] * (excl + s);
    }
}

#define DMA_ROW(b, prow, irow)                        \
    dma16((prow) + 0,  &ring[b][0][0]);               \
    dma16((prow) + 4,  &ring[b][0][256]);             \
    dma16((prow) + 8,  &ring[b][0][512]);             \
    dma16((prow) + 12, &ring[b][0][768]);             \
    dma16((irow) + 0,  &ring[b][1][0]);               \
    dma16((irow) + 4,  &ring[b][1][256]);             \
    dma16((irow) + 8,  &ring[b][1][512]);             \
    dma16((irow) + 12, &ring[b][1][768]);

#define READ_ROW(b, G)                                   \
    p##G##0 = *(const f32x4*)&ring[b][0][0   + l4];      \
    p##G##1 = *(const f32x4*)&ring[b][0][256 + l4];      \
    p##G##2 = *(const f32x4*)&ring[b][0][512 + l4];      \
    p##G##3 = *(const f32x4*)&ring[b][0][768 + l4];      \
    i##G##0 = *(const f32x4*)&ring[b][1][0   + l4];      \
    i##G##1 = *(const f32x4*)&ring[b][1][256 + l4];      \
    i##G##2 = *(const f32x4*)&ring[b][1][512 + l4];      \
    i##G##3 = *(const f32x4*)&ring[b][1][768 + l4];

#define STEP(WAITN, BUFC, BUFN, DO_READ, DO_DMA, CG, NG)              \
    {                                                                 \
        vwait<WAITN>();                                               \
        if (DO_READ) { READ_ROW(BUFN, NG) }                           \
        alpha_step(p##CG##0, p##CG##1, p##CG##2, p##CG##3,            \
                   i##CG##0, i##CG##1, i##CG##2, i##CG##3, a);        \
        *(f32x4*)(st + 0)  = *(const f32x4*)&a[0];                    \
        *(f32x4*)(st + 4)  = *(const f32x4*)&a[4];                    \
        *(f32x4*)(st + 8)  = *(const f32x4*)&a[8];                    \
        *(f32x4*)(st + 12) = *(const f32x4*)&a[12];                   \
        st += KLEN;                                                   \
        if (DO_DMA) {                                                 \
            __builtin_amdgcn_sched_barrier(0);                        \
            DMA_ROW(BUFC, np, ni)                                     \
            np += KLEN; ni += KLEN;                                   \
        }                                                             \
    }

__global__ __launch_bounds__(64) void alpha_kernel(float* __restrict__ PCP,
                                                   const float* __restrict__ ICP)
{
    __shared__ float ring[8][2][1024];   // 64 KB

    const int z = blockIdx.x;
    float* base = PCP + (size_t)z * QLEN * KLEN;
    const float* ibase = ICP + (size_t)z * QLEN * KLEN;
    const int lane = threadIdx.x;
    const int col = lane * 16;
    const int l4 = lane * 4;

    {
        const float* pp = base + col;
        const float* ip = ibase + col;
        DMA_ROW(0, pp, ip) pp += KLEN; ip += KLEN;
        DMA_ROW(1, pp, ip) pp += KLEN; ip += KLEN;
        DMA_ROW(2, pp, ip) pp += KLEN; ip += KLEN;
        DMA_ROW(3, pp, ip) pp += KLEN; ip += KLEN;
        DMA_ROW(4, pp, ip) pp += KLEN; ip += KLEN;
        DMA_ROW(5, pp, ip) pp += KLEN; ip += KLEN;
        DMA_ROW(6, pp, ip) pp += KLEN; ip += KLEN;
        DMA_ROW(7, pp, ip)
    }

    f32x4 pA0, pA1, pA2, pA3, iA0, iA1, iA2, iA3;
    f32x4 pB0, pB1, pB2, pB3, iB0, iB1, iB2, iB3;

    vwait<56>();
    READ_ROW(0, A)

    float a[16];
#pragma unroll
    for (int j = 0; j < 16; ++j) a[j] = 0.0f;
    if (lane == 0) a[0] = 1.0f;

    float* st = base + col;
    const float* np = base + (size_t)8 * KLEN + col;
    const float* ni = ibase + (size_t)8 * KLEN + col;

    for (int it = 0; it < 63; ++it) {
        STEP(48, 0, 1, true, true, A, B)
        STEP(48, 1, 2, true, true, B, A)
        STEP(48, 2, 3, true, true, A, B)
        STEP(48, 3, 4, true, true, B, A)
        STEP(48, 4, 5, true, true, A, B)
        STEP(48, 5, 6, true, true, B, A)
        STEP(48, 6, 7, true, true, A, B)
        STEP(48, 7, 0, true, true, B, A)
    }

    STEP(48, 0, 1, true, false, A, B)      // q=504
    STEP(40, 1, 2, true, false, B, A)      // q=505
    STEP(32, 2, 3, true, false, A, B)      // q=506
    STEP(24, 3, 4, true, false, B, A)      // q=507
    STEP(16, 4, 5, true, false, A, B)      // q=508
    STEP(8,  5, 6, true, false, B, A)      // q=509
    STEP(0,  6, 7, true, false, A, B)      // q=510
    STEP(0,  7, 0, false, false, B, A)     // q=511
}

// beta[b,hca,q,k] = se * movsum_fwd3(alpha[b,hma,q,:]/den[b,hca,q,:]) for fixed hma
__global__ __launch_bounds__(256) void beta_kernel(
    const float* __restrict__ ALPHA, const float* __restrict__ SE,
    const float* __restrict__ DEN, float* __restrict__ BETA, int hma)
{
    const int rowi = blockIdx.x;
    const int q  = rowi & (QLEN - 1);
    const int bh = rowi >> 9;
    const int hca = bh & (H_CA - 1);
    const int b  = bh >> 1;

    const float* arow = ALPHA + ((((size_t)b * H_MA + hma) * QLEN + q) * KLEN);
    const float* srow = SE  + (size_t)rowi * KLEN;
    const float* drow = DEN + (size_t)rowi * KLEN;
    float* brow = BETA + (size_t)rowi * KLEN;

    __shared__ float ad[KLEN + CHUNK - 1];
    const int tid = threadIdx.x;
    const float4 a4 = *(const float4*)(arow + tid * 4);
    const float4 d4 = *(const float4*)(drow + tid * 4);
    const float ar[4] = {a4.x, a4.y, a4.z, a4.w};
    const float dr[4] = {d4.x, d4.y, d4.z, d4.w};
#pragma unroll
    for (int j = 0; j < 4; ++j)
        ad[tid * 4 + j] = ar[j] / dr[j];
    if (tid < CHUNK - 1) ad[KLEN + tid] = 0.0f;
    __syncthreads();

    const float4 s4 = *(const float4*)(srow + tid * 4);
    const float sr[4] = {s4.x, s4.y, s4.z, s4.w};
    float4 o;
    float* op = (float*)&o;
#pragma unroll
    for (int j = 0; j < 4; ++j) {
        const int k = tid * 4 + j;
        op[j] = sr[j] * (ad[k] + ad[k + 1] + ad[k + 2] + ad[k + 3]);
    }
    *(float4*)(brow + tid * 4) = o;
}

__global__ __launch_bounds__(256) void cv_gemm_kernel(
    const float* __restrict__ BETA, const float* __restrict__ VP,
    float* __restrict__ CV, int hma)
{
    const int z = blockIdx.y;
    const int b = z / H_CA;
    const int hca = z - b * H_CA;
    const int h = hma * H_CA + hca;
    const float* A  = BETA + (size_t)z * QLEN * KLEN;
    const float* Bm = VP + (size_t)b * KLEN * DIM + h * 64;
    float* C = CV + (size_t)b * QLEN * DIM + h * 64;
    gemm_nn_tile(A, KLEN, Bm, DIM, C, DIM, KLEN, nullptr, blockIdx.x * 64, 0);
}

// ---------------------------------------------------------------------------

extern "C" void kernel_launch(void* const* d_in, const int* in_sizes, int n_in,
                              void* d_out, int out_size, void* d_ws, size_t ws_size,
                              hipStream_t stream)
{
    (void)in_sizes; (void)n_in; (void)out_size; (void)ws_size;
    const float* key_t = (const float*)d_in[0];
    const float* query = (const float*)d_in[1];
    const float* wk_ma = (const float*)d_in[2];
    const float* bk_ma = (const float*)d_in[3];
    const float* wq_ma = (const float*)d_in[4];
    const float* bq_ma = (const float*)d_in[5];
    const float* r     = (const float*)d_in[6];
    const float* wk_ca = (const float*)d_in[7];
    const float* bk_ca = (const float*)d_in[8];
    const float* wq_ca = (const float*)d_in[9];
    const float* bq_ca = (const float*)d_in[10];
    const float* wv    = (const float*)d_in[11];
    const float* bv    = (const float*)d_in[12];
    const float* wo    = (const float*)d_in[13];
    const float* bo    = (const float*)d_in[14];
    float* out = (float*)d_out;

    float* ws = (float*)d_ws;
    size_t off = 0;
    float* KP_MA = ws + off; off += (size_t)B_ * KLEN * DIM;
    float* QP_MA = ws + off; off += (size_t)B_ * QLEN * DIM;
    float* KP_CA = ws + off; off += (size_t)B_ * KLEN * DIM;
    float* QP_CA = ws + off; off += (size_t)B_ * QLEN * DIM;
    float* VP    = ws + off; off += (size_t)B_ * KLEN * DIM;
    float* PCP   = ws + off; off += (size_t)B_ * H_MA * QLEN * KLEN;
    float* ICP   = ws + off; off += (size_t)B_ * H_MA * QLEN * KLEN;
    float* SE    = ws + off; off += (size_t)B_ * H_CA * QLEN * KLEN;
    float* DEN   = ws + off; off += (size_t)B_ * H_CA * QLEN * KLEN;
    float* BETA  = ws + off; off += (size_t)B_ * H_CA * QLEN * KLEN;
    float* CV    = ws + off; off += (size_t)B_ * QLEN * DIM;

    const dim3 blk(256);

    // projections (fp32 128x128 NN GEMMs, K=512)
    gemm128_nn_kernel<<<dim3(B_ * KLEN / 128, DIM / 128), blk, 0, stream>>>(key_t, DIM, wk_ma, DIM, KP_MA, DIM, DIM, bk_ma);
    gemm128_nn_kernel<<<dim3(B_ * QLEN / 128, DIM / 128), blk, 0, stream>>>(query, DIM, wq_ma, DIM, QP_MA, DIM, DIM, bq_ma);
    gemm128_nn_kernel<<<dim3(B_ * KLEN / 128, DIM / 128), blk, 0, stream>>>(key_t, DIM, wk_ca, DIM, KP_CA, DIM, DIM, bk_ca);
    gemm128_nn_kernel<<<dim3(B_ * QLEN / 128, DIM / 128), blk, 0, stream>>>(query, DIM, wq_ca, DIM, QP_CA, DIM, DIM, bq_ca);
    gemm128_nn_kernel<<<dim3(B_ * KLEN / 128, DIM / 128), blk, 0, stream>>>(key_t, DIM, wv, DIM, VP, DIM, DIM, bv);

    // energies (128x128 NT, batched over (b,h))
    energy128_nt_kernel<<<dim3(QLEN / 128, KLEN / 128, B_ * H_MA), blk, 0, stream>>>(QP_MA, KP_MA, PCP, H_MA, DIM / H_MA, r);
    energy128_nt_kernel<<<dim3(QLEN / 128, KLEN / 128, B_ * H_CA), blk, 0, stream>>>(QP_CA, KP_CA, SE, H_CA, DIM / H_CA, nullptr);

    // row transforms
    ma_row_kernel<<<dim3(B_ * H_MA * QLEN), blk, 0, stream>>>(PCP, ICP);
    ca_row_kernel<<<dim3(B_ * H_CA * QLEN), blk, 0, stream>>>(SE, DEN);

    // monotonic alignment recurrence (round-8 LDS-ring version)
    alpha_kernel<<<dim3(B_ * H_MA), dim3(64), 0, stream>>>(PCP, ICP);

    // beta + context GEMM, chunked over h_ma
    for (int hma = 0; hma < H_MA; ++hma) {
        beta_kernel<<<dim3(B_ * H_CA * QLEN), blk, 0, stream>>>(PCP, SE, DEN, BETA, hma);
        cv_gemm_kernel<<<dim3(QLEN / 64, B_ * H_CA), blk, 0, stream>>>(BETA, VP, CV, hma);
    }

    // output projection
    gemm128_nn_kernel<<<dim3(B_ * QLEN / 128, DIM / 128), blk, 0, stream>>>(CV, DIM, wo, DIM, out, DIM, DIM, bo);
}

// Round 11
// 573.822 us; speedup vs baseline: 1.7122x; 1.7122x over previous
//
#include <hip/hip_runtime.h>
#include <hip/hip_bf16.h>
#include <math.h>

#define DEV_INLINE __device__ __forceinline__

typedef float f32x4 __attribute__((ext_vector_type(4)));

constexpr int B_    = 4;
constexpr int QLEN  = 512;
constexpr int KLEN  = 1024;
constexpr int DIM   = 512;
constexpr int H_MA  = 4;
constexpr int H_CA  = 2;
constexpr int CHUNK = 4;
constexpr float EPS = 1e-6f;
constexpr float INV_SCALE = 1.0f / 22.62741699796952f;  // 1/sqrt(512)

// ---------------------------------------------------------------------------
// 64x64 fp32 GEMM tiles (BK=16, 256 threads, 4x4/thread) — round-8 verified
// ---------------------------------------------------------------------------

DEV_INLINE void gemm_nn_tile(const float* __restrict__ A, int lda,
                             const float* __restrict__ Bm, int ldb,
                             float* __restrict__ C, int ldc,
                             int K, const float* __restrict__ bias,
                             int bm, int bn)
{
    __shared__ float As[16][68];
    __shared__ float Bs[16][68];
    const int tid  = threadIdx.x;
    const int tm   = (tid >> 4) << 2;
    const int tn   = (tid & 15) << 2;
    const int arow = tid >> 2;
    const int acol = (tid & 3) << 2;
    const int brow = tid >> 4;
    const int bcol = (tid & 15) << 2;
    float acc[4][4] = {};

    for (int k0 = 0; k0 < K; k0 += 16) {
        const float4 av = *(const float4*)(A + (size_t)(bm + arow) * lda + k0 + acol);
        const float4 bv = *(const float4*)(Bm + (size_t)(k0 + brow) * ldb + bn + bcol);
        __syncthreads();
        As[acol + 0][arow] = av.x;
        As[acol + 1][arow] = av.y;
        As[acol + 2][arow] = av.z;
        As[acol + 3][arow] = av.w;
        *(float4*)(&Bs[brow][bcol]) = bv;
        __syncthreads();
#pragma unroll
        for (int kk = 0; kk < 16; ++kk) {
            const float4 a = *(const float4*)&As[kk][tm];
            const float4 b = *(const float4*)&Bs[kk][tn];
            const float ar[4] = {a.x, a.y, a.z, a.w};
            const float br[4] = {b.x, b.y, b.z, b.w};
#pragma unroll
            for (int i = 0; i < 4; ++i)
#pragma unroll
                for (int j = 0; j < 4; ++j)
                    acc[i][j] = fmaf(ar[i], br[j], acc[i][j]);
        }
    }
#pragma unroll
    for (int i = 0; i < 4; ++i) {
        float4 o;
        float* op = (float*)&o;
#pragma unroll
        for (int j = 0; j < 4; ++j)
            op[j] = acc[i][j] + (bias ? bias[bn + tn + j] : 0.0f);
        *(float4*)(C + (size_t)(bm + tm + i) * ldc + bn + tn) = o;
    }
}

DEV_INLINE void gemm_nt_tile(const float* __restrict__ A, int lda,
                             const float* __restrict__ Bm, int ldb,
                             float* __restrict__ C, int ldc,
                             int K, float scale, float addv,
                             int bm, int bn)
{
    __shared__ float As[16][68];
    __shared__ float Bs[16][68];
    const int tid = threadIdx.x;
    const int tm  = (tid >> 4) << 2;
    const int tn  = (tid & 15) << 2;
    const int row = tid >> 2;
    const int col = (tid & 3) << 2;
    float acc[4][4] = {};

    for (int k0 = 0; k0 < K; k0 += 16) {
        const float4 av = *(const float4*)(A + (size_t)(bm + row) * lda + k0 + col);
        const float4 bv = *(const float4*)(Bm + (size_t)(bn + row) * ldb + k0 + col);
        __syncthreads();
        As[col + 0][row] = av.x;
        As[col + 1][row] = av.y;
        As[col + 2][row] = av.z;
        As[col + 3][row] = av.w;
        Bs[col + 0][row] = bv.x;
        Bs[col + 1][row] = bv.y;
        Bs[col + 2][row] = bv.z;
        Bs[col + 3][row] = bv.w;
        __syncthreads();
#pragma unroll
        for (int kk = 0; kk < 16; ++kk) {
            const float4 a = *(const float4*)&As[kk][tm];
            const float4 b = *(const float4*)&Bs[kk][tn];
            const float ar[4] = {a.x, a.y, a.z, a.w};
            const float br[4] = {b.x, b.y, b.z, b.w};
#pragma unroll
            for (int i = 0; i < 4; ++i)
#pragma unroll
                for (int j = 0; j < 4; ++j)
                    acc[i][j] = fmaf(ar[i], br[j], acc[i][j]);
        }
    }
#pragma unroll
    for (int i = 0; i < 4; ++i) {
        float4 o;
        float* op = (float*)&o;
#pragma unroll
        for (int j = 0; j < 4; ++j)
            op[j] = acc[i][j] * scale + addv;
        *(float4*)(C + (size_t)(bm + tm + i) * ldc + bn + tn) = o;
    }
}

// ---------------------------------------------------------------------------

__global__ __launch_bounds__(256) void gemm_nn_kernel(
    const float* __restrict__ A, int lda,
    const float* __restrict__ Bm, int ldb,
    float* __restrict__ C, int ldc,
    int K, const float* __restrict__ bias)
{
    gemm_nn_tile(A, lda, Bm, ldb, C, ldc, K, bias, blockIdx.x * 64, blockIdx.y * 64);
}

__global__ __launch_bounds__(256) void energy_nt_kernel(
    const float* __restrict__ QP, const float* __restrict__ KP,
    float* __restrict__ E, int H, int HD, const float* __restrict__ radd)
{
    const int z = blockIdx.z;
    const int b = z / H;
    const int h = z - b * H;
    const float* A  = QP + (size_t)b * QLEN * DIM + h * HD;
    const float* Bm = KP + (size_t)b * KLEN * DIM + h * HD;
    float* C = E + (size_t)z * QLEN * KLEN;
    const float addv = radd ? radd[0] : 0.0f;
    gemm_nt_tile(A, DIM, Bm, DIM, C, KLEN, HD, INV_SCALE, addv,
                 blockIdx.x * 64, blockIdx.y * 64);
}

__global__ __launch_bounds__(256) void ma_row_kernel(float* __restrict__ PCP,
                                                     float* __restrict__ ICP)
{
    const size_t row = blockIdx.x;
    float* pe = PCP + row * KLEN;
    float* pi = ICP + row * KLEN;
    const int tid = threadIdx.x;
    const int lane = tid & 63, wid = tid >> 6;

    const float4 ev = *(const float4*)(pe + tid * 4);
    float e[4] = {ev.x, ev.y, ev.z, ev.w};
    float p[4], l[4], s[4];
    float run = 0.0f;
#pragma unroll
    for (int j = 0; j < 4; ++j) {
        p[j] = 1.0f / (1.0f + expf(-e[j]));
        float om = 1.0f - p[j];
        om = fminf(fmaxf(om, EPS), 1.0f);
        l[j] = logf(om);
        run += l[j];
        s[j] = run;
    }
    const float t = run;
    float v = t;
#pragma unroll
    for (int off = 1; off < 64; off <<= 1) {
        const float u = __shfl_up(v, off);
        if (lane >= off) v += u;
    }
    __shared__ float wsum[4];
    if (lane == 63) wsum[wid] = v;
    __syncthreads();
    float base = v - t;
    for (int w = 0; w < wid; ++w) base += wsum[w];

    float4 po, io;
    float* pp = (float*)&po;
    float* ip = (float*)&io;
#pragma unroll
    for (int j = 0; j < 4; ++j) {
        const float cum = base + s[j];
        const float cp  = expf(cum - l[j]);
        pp[j] = p[j] * cp;
        ip[j] = 1.0f / fmaxf(cp, EPS);
    }
    *(float4*)(pe + tid * 4) = po;
    *(float4*)(pi + tid * 4) = io;
}

__global__ __launch_bounds__(256) void ca_row_kernel(float* __restrict__ SE,
                                                     float* __restrict__ DEN)
{
    const size_t row = blockIdx.x;
    float* ps = SE + row * KLEN;
    float* pd = DEN + row * KLEN;
    const int tid = threadIdx.x;
    const int lane = tid & 63, wid = tid >> 6;

    const float4 ev = *(const float4*)(ps + tid * 4);
    float e[4] = {ev.x, ev.y, ev.z, ev.w};
    float m = fmaxf(fmaxf(e[0], e[1]), fmaxf(e[2], e[3]));
#pragma unroll
    for (int off = 32; off >= 1; off >>= 1)
        m = fmaxf(m, __shfl_xor(m, off));
    __shared__ float wmax[4];
    if (lane == 0) wmax[wid] = m;
    __syncthreads();
    m = fmaxf(fmaxf(wmax[0], wmax[1]), fmaxf(wmax[2], wmax[3]));

    __shared__ float sh[KLEN + 3];
    if (tid < 3) sh[tid] = 0.0f;
    float se[4];
#pragma unroll
    for (int j = 0; j < 4; ++j) {
        se[j] = fmaxf(expf(e[j] - m), 1e-5f);
        sh[3 + tid * 4 + j] = se[j];
    }
    __syncthreads();
    float4 so, do_;
    float* sp = (float*)&so;
    float* dp = (float*)&do_;
#pragma unroll
    for (int j = 0; j < 4; ++j) {
        const int k = tid * 4 + j;
        sp[j] = se[j];
        dp[j] = sh[3 + k] + sh[2 + k] + sh[1 + k] + sh[k];
    }
    *(float4*)(ps + tid * 4) = so;
    *(float4*)(pd + tid * 4) = do_;
}

// ---------------------------------------------------------------------------
// alpha recurrence: single wave per (b,h_ma), DPP wave scan.
// TWO distinct __shared__ ring halves (4 rows each) filled by global_load_lds:
// distinct LDS objects give the waitcnt pass static alias info, so ds_reads
// of one half need not drain DMAs targeting the other half (round-8's
// single-object ring forced a vmcnt(0) drain per step = one full latency).
// Counted vmcnt per 4-row super-step; conservative with stores in counter.
// ---------------------------------------------------------------------------

template<int CTRL, int ROW_MASK>
DEV_INLINE float dpp_add(float x) {
    int t = __builtin_amdgcn_update_dpp(0, __float_as_int(x), CTRL, ROW_MASK, 0xf, true);
    return x + __int_as_float(t);
}

DEV_INLINE float wave64_incl_scan(float x) {
    x = dpp_add<0x111, 0xf>(x);  // row_shr:1
    x = dpp_add<0x112, 0xf>(x);  // row_shr:2
    x = dpp_add<0x114, 0xf>(x);  // row_shr:4
    x = dpp_add<0x118, 0xf>(x);  // row_shr:8
    x = dpp_add<0x142, 0xa>(x);  // row_bcast:15 -> rows 1,3
    x = dpp_add<0x143, 0xc>(x);  // row_bcast:31 -> rows 2,3
    return x;
}

typedef __attribute__((address_space(3))) void lv_t;
typedef __attribute__((address_space(1))) const void gv_t;

DEV_INLINE void dma16(const float* g, float* l) {
    __builtin_amdgcn_global_load_lds((gv_t*)g, (lv_t*)l, 16, 0, 0);
}

template<int N> DEV_INLINE void vwait() {
    asm volatile("s_waitcnt vmcnt(%0)" :: "i"(N) : "memory");
    __builtin_amdgcn_sched_barrier(0);
}

DEV_INLINE void alpha_step(const f32x4& P0, const f32x4& P1,
                           const f32x4& P2, const f32x4& P3,
                           const f32x4& I0, const f32x4& I1,
                           const f32x4& I2, const f32x4& I3,
                           float (&a)[16])
{
    float pc[16], ic[16];
    *(f32x4*)&pc[0] = P0; *(f32x4*)&pc[4] = P1;
    *(f32x4*)&pc[8] = P2; *(f32x4*)&pc[12] = P3;
    *(f32x4*)&ic[0] = I0; *(f32x4*)&ic[4] = I1;
    *(f32x4*)&ic[8] = I2; *(f32x4*)&ic[12] = I3;

    float t[16];
#pragma unroll
    for (int j = 0; j < 16; ++j) t[j] = a[j] * ic[j];

    float u1[8], u2[4];
#pragma unroll
    for (int j = 0; j < 8; ++j) u1[j] = t[2 * j] + t[2 * j + 1];
#pragma unroll
    for (int j = 0; j < 4; ++j) u2[j] = u1[2 * j] + u1[2 * j + 1];
    const float tot = (u2[0] + u2[1]) + (u2[2] + u2[3]);

    const float incl = wave64_incl_scan(tot);
    const float excl = incl - tot;

    float s = 0.0f;
#pragma unroll
    for (int j = 0; j < 16; ++j) {
        s += t[j];
        a[j] = pc[j] * (excl + s);
    }
}

// DMA one row-pair into ring R, slot b. prow/irow include +lane*16.
#define DMA_ROW(R, b, prow, irow)                     \
    dma16((prow) + 0,  &R[b][0][0]);                  \
    dma16((prow) + 4,  &R[b][0][256]);                \
    dma16((prow) + 8,  &R[b][0][512]);                \
    dma16((prow) + 12, &R[b][0][768]);                \
    dma16((irow) + 0,  &R[b][1][0]);                  \
    dma16((irow) + 4,  &R[b][1][256]);                \
    dma16((irow) + 8,  &R[b][1][512]);                \
    dma16((irow) + 12, &R[b][1][768]);

#define READ_ROW(R, b, G)                                \
    p##G##0 = *(const f32x4*)&R[b][0][0   + l4];         \
    p##G##1 = *(const f32x4*)&R[b][0][256 + l4];         \
    p##G##2 = *(const f32x4*)&R[b][0][512 + l4];         \
    p##G##3 = *(const f32x4*)&R[b][0][768 + l4];         \
    i##G##0 = *(const f32x4*)&R[b][1][0   + l4];         \
    i##G##1 = *(const f32x4*)&R[b][1][256 + l4];         \
    i##G##2 = *(const f32x4*)&R[b][1][512 + l4];         \
    i##G##3 = *(const f32x4*)&R[b][1][768 + l4];

#define COMP_ST(G)                                                    \
    alpha_step(p##G##0, p##G##1, p##G##2, p##G##3,                    \
               i##G##0, i##G##1, i##G##2, i##G##3, a);                \
    *(f32x4*)(st + 0)  = *(const f32x4*)&a[0];                        \
    *(f32x4*)(st + 4)  = *(const f32x4*)&a[4];                        \
    *(f32x4*)(st + 8)  = *(const f32x4*)&a[8];                        \
    *(f32x4*)(st + 12) = *(const f32x4*)&a[12];                       \
    st += KLEN;

// one 4-row super-step on ring R: reads interleaved with computes, then
// (optionally) refill R with the 4 rows 8 ahead.
#define SS(R, WAITN, DO_DMA)                                          \
    {                                                                 \
        vwait<WAITN>();                                               \
        READ_ROW(R, 0, A)                                             \
        READ_ROW(R, 1, B)                                             \
        COMP_ST(A)                                                    \
        READ_ROW(R, 2, A)                                             \
        COMP_ST(B)                                                    \
        READ_ROW(R, 3, B)                                             \
        COMP_ST(A)                                                    \
        COMP_ST(B)                                                    \
        if (DO_DMA) {                                                 \
            __builtin_amdgcn_sched_barrier(0);                        \
            DMA_ROW(R, 0, np, ni)                                     \
            DMA_ROW(R, 1, np + KLEN, ni + KLEN)                       \
            DMA_ROW(R, 2, np + 2 * KLEN, ni + 2 * KLEN)               \
            DMA_ROW(R, 3, np + 3 * KLEN, ni + 3 * KLEN)               \
            np += 4 * KLEN; ni += 4 * KLEN;                           \
        }                                                             \
    }

__global__ __launch_bounds__(64) void alpha_kernel(float* __restrict__ PCP,
                                                   const float* __restrict__ ICP)
{
    __shared__ float ringA[4][2][1024];   // 32 KB  (distinct objects!)
    __shared__ float ringB[4][2][1024];   // 32 KB

    const int z = blockIdx.x;
    float* base = PCP + (size_t)z * QLEN * KLEN;
    const float* ibase = ICP + (size_t)z * QLEN * KLEN;
    const int lane = threadIdx.x;
    const int col = lane * 16;
    const int l4 = lane * 4;

    // prologue: rows 0..3 -> ringA, rows 4..7 -> ringB (64 loads)
    {
        const float* pp = base + col;
        const float* ip = ibase + col;
        DMA_ROW(ringA, 0, pp, ip) pp += KLEN; ip += KLEN;
        DMA_ROW(ringA, 1, pp, ip) pp += KLEN; ip += KLEN;
        DMA_ROW(ringA, 2, pp, ip) pp += KLEN; ip += KLEN;
        DMA_ROW(ringA, 3, pp, ip) pp += KLEN; ip += KLEN;
        DMA_ROW(ringB, 0, pp, ip) pp += KLEN; ip += KLEN;
        DMA_ROW(ringB, 1, pp, ip) pp += KLEN; ip += KLEN;
        DMA_ROW(ringB, 2, pp, ip) pp += KLEN; ip += KLEN;
        DMA_ROW(ringB, 3, pp, ip)
    }

    f32x4 pA0, pA1, pA2, pA3, iA0, iA1, iA2, iA3;
    f32x4 pB0, pB1, pB2, pB3, iB0, iB1, iB2, iB3;

    float a[16];
#pragma unroll
    for (int j = 0; j < 16; ++j) a[j] = 0.0f;
    if (lane == 0) a[0] = 1.0f;

    float* st = base + col;
    const float* np = base + (size_t)8 * KLEN + col;
    const float* ni = ibase + (size_t)8 * KLEN + col;

    // super-steps 0..125 (refilling), 126..127 (drain). SS it handles rows
    // 4it..4it+3 from ring(it&1); refill targets rows 4it+8..4it+11.
    for (int it2 = 0; it2 < 63; ++it2) {
        SS(ringA, 32, true)
        SS(ringB, 32, true)
    }
    SS(ringA, 32, false)   // rows 504..507 (ringB's refill still in flight)
    SS(ringB, 0, false)    // rows 508..511 (last; drain)
}

// ---------------------------------------------------------------------------
// fused beta+cv: CV[b,q,h*64..] = beta(b,h) @ V(b,h), beta computed on the
// fly in the A-tile staging: beta[q,k] = se[q,k] * sum_{i=0..3} ad[q,k+i],
// ad = alpha/den zero-padded past KLEN (matches moving_sum fwd window).
// One launch, grid (QLEN/64, B_*H_MA*H_CA) = (8, 32) = 256 blocks.
// ---------------------------------------------------------------------------

__global__ __launch_bounds__(256) void fused_cv_kernel(
    const float* __restrict__ ALPHA, const float* __restrict__ SE,
    const float* __restrict__ DEN, const float* __restrict__ VP,
    float* __restrict__ CV)
{
    const int z = blockIdx.y;          // b*8 + hma*2 + hca
    const int b = z >> 3;
    const int h = z & 7;
    const int hma = h >> 1;
    const int hca = h & 1;
    const int bm = blockIdx.x * 64;

    const float* a_base  = ALPHA + ((size_t)b * H_MA + hma) * QLEN * KLEN;
    const float* se_base = SE  + ((size_t)b * H_CA + hca) * QLEN * KLEN;
    const float* dn_base = DEN + ((size_t)b * H_CA + hca) * QLEN * KLEN;
    const float* Bm = VP + (size_t)b * KLEN * DIM + h * 64;   // ldb = DIM
    float* C = CV + (size_t)b * QLEN * DIM + h * 64;          // ldc = DIM

    __shared__ float As[16][68];
    __shared__ float Bs[16][68];
    const int tid  = threadIdx.x;
    const int tm   = (tid >> 4) << 2;
    const int tn   = (tid & 15) << 2;
    const int arow = tid >> 2;          // 0..63
    const int acol = (tid & 3) << 2;    // 0,4,8,12
    const int brow = tid >> 4;          // 0..15
    const int bcol = (tid & 15) << 2;
    float acc[4][4] = {};

    for (int k0 = 0; k0 < KLEN; k0 += 16) {
        const int ka = k0 + acol;
        const size_t roff = (size_t)(bm + arow) * KLEN;
        const f32x4 sev = *(const f32x4*)(se_base + roff + ka);
        const f32x4 al0 = *(const f32x4*)(a_base + roff + ka);
        const f32x4 dn0 = *(const f32x4*)(dn_base + roff + ka);
        f32x4 al1 = {0.0f, 0.0f, 0.0f, 0.0f};
        f32x4 dn1 = {1.0f, 1.0f, 1.0f, 1.0f};
        if (ka + 4 < KLEN) {
            al1 = *(const f32x4*)(a_base + roff + ka + 4);
            dn1 = *(const f32x4*)(dn_base + roff + ka + 4);
        }
        float ad[7];
#pragma unroll
        for (int j = 0; j < 4; ++j) ad[j] = al0[j] / dn0[j];
#pragma unroll
        for (int j = 0; j < 3; ++j) ad[4 + j] = al1[j] / dn1[j];
        const float4 bv = *(const float4*)(Bm + (size_t)(k0 + brow) * DIM + bcol);
        __syncthreads();
        As[acol + 0][arow] = sev[0] * (ad[0] + ad[1] + ad[2] + ad[3]);
        As[acol + 1][arow] = sev[1] * (ad[1] + ad[2] + ad[3] + ad[4]);
        As[acol + 2][arow] = sev[2] * (ad[2] + ad[3] + ad[4] + ad[5]);
        As[acol + 3][arow] = sev[3] * (ad[3] + ad[4] + ad[5] + ad[6]);
        *(float4*)(&Bs[brow][bcol]) = bv;
        __syncthreads();
#pragma unroll
        for (int kk = 0; kk < 16; ++kk) {
            const float4 av = *(const float4*)&As[kk][tm];
            const float4 bw = *(const float4*)&Bs[kk][tn];
            const float ar[4] = {av.x, av.y, av.z, av.w};
            const float br[4] = {bw.x, bw.y, bw.z, bw.w};
#pragma unroll
            for (int i = 0; i < 4; ++i)
#pragma unroll
                for (int j = 0; j < 4; ++j)
                    acc[i][j] = fmaf(ar[i], br[j], acc[i][j]);
        }
    }
#pragma unroll
    for (int i = 0; i < 4; ++i) {
        float4 o;
        float* op = (float*)&o;
#pragma unroll
        for (int j = 0; j < 4; ++j)
            op[j] = acc[i][j];
        *(float4*)(C + (size_t)(bm + tm + i) * DIM + tn) = o;
    }
}

// ---------------------------------------------------------------------------

extern "C" void kernel_launch(void* const* d_in, const int* in_sizes, int n_in,
                              void* d_out, int out_size, void* d_ws, size_t ws_size,
                              hipStream_t stream)
{
    (void)in_sizes; (void)n_in; (void)out_size; (void)ws_size;
    const float* key_t = (const float*)d_in[0];
    const float* query = (const float*)d_in[1];
    const float* wk_ma = (const float*)d_in[2];
    const float* bk_ma = (const float*)d_in[3];
    const float* wq_ma = (const float*)d_in[4];
    const float* bq_ma = (const float*)d_in[5];
    const float* r     = (const float*)d_in[6];
    const float* wk_ca = (const float*)d_in[7];
    const float* bk_ca = (const float*)d_in[8];
    const float* wq_ca = (const float*)d_in[9];
    const float* bq_ca = (const float*)d_in[10];
    const float* wv    = (const float*)d_in[11];
    const float* bv    = (const float*)d_in[12];
    const float* wo    = (const float*)d_in[13];
    const float* bo    = (const float*)d_in[14];
    float* out = (float*)d_out;

    float* ws = (float*)d_ws;
    size_t off = 0;
    float* KP_MA = ws + off; off += (size_t)B_ * KLEN * DIM;
    float* QP_MA = ws + off; off += (size_t)B_ * QLEN * DIM;
    float* KP_CA = ws + off; off += (size_t)B_ * KLEN * DIM;
    float* QP_CA = ws + off; off += (size_t)B_ * QLEN * DIM;
    float* VP    = ws + off; off += (size_t)B_ * KLEN * DIM;
    float* PCP   = ws + off; off += (size_t)B_ * H_MA * QLEN * KLEN;
    float* ICP   = ws + off; off += (size_t)B_ * H_MA * QLEN * KLEN;
    float* SE    = ws + off; off += (size_t)B_ * H_CA * QLEN * KLEN;
    float* DEN   = ws + off; off += (size_t)B_ * H_CA * QLEN * KLEN;
    float* CV    = ws + off; off += (size_t)B_ * QLEN * DIM;

    const dim3 blk(256);

    // projections (fp32 64x64 NN GEMMs, K=512)
    gemm_nn_kernel<<<dim3(B_ * KLEN / 64, DIM / 64), blk, 0, stream>>>(key_t, DIM, wk_ma, DIM, KP_MA, DIM, DIM, bk_ma);
    gemm_nn_kernel<<<dim3(B_ * QLEN / 64, DIM / 64), blk, 0, stream>>>(query, DIM, wq_ma, DIM, QP_MA, DIM, DIM, bq_ma);
    gemm_nn_kernel<<<dim3(B_ * KLEN / 64, DIM / 64), blk, 0, stream>>>(key_t, DIM, wk_ca, DIM, KP_CA, DIM, DIM, bk_ca);
    gemm_nn_kernel<<<dim3(B_ * QLEN / 64, DIM / 64), blk, 0, stream>>>(query, DIM, wq_ca, DIM, QP_CA, DIM, DIM, bq_ca);
    gemm_nn_kernel<<<dim3(B_ * KLEN / 64, DIM / 64), blk, 0, stream>>>(key_t, DIM, wv, DIM, VP, DIM, DIM, bv);

    // energies (NT batched over (b,h))
    energy_nt_kernel<<<dim3(QLEN / 64, KLEN / 64, B_ * H_MA), blk, 0, stream>>>(QP_MA, KP_MA, PCP, H_MA, DIM / H_MA, r);
    energy_nt_kernel<<<dim3(QLEN / 64, KLEN / 64, B_ * H_CA), blk, 0, stream>>>(QP_CA, KP_CA, SE, H_CA, DIM / H_CA, nullptr);

    // row transforms
    ma_row_kernel<<<dim3(B_ * H_MA * QLEN), blk, 0, stream>>>(PCP, ICP);
    ca_row_kernel<<<dim3(B_ * H_CA * QLEN), blk, 0, stream>>>(SE, DEN);

    // monotonic alignment recurrence (two-object LDS ring)
    alpha_kernel<<<dim3(B_ * H_MA), dim3(64), 0, stream>>>(PCP, ICP);

    // fused beta+cv: one launch over all heads
    fused_cv_kernel<<<dim3(QLEN / 64, B_ * H_MA * H_CA), blk, 0, stream>>>(PCP, SE, DEN, VP, CV);

    // output projection
    gemm_nn_kernel<<<dim3(B_ * QLEN / 64, DIM / 64), blk, 0, stream>>>(CV, DIM, wo, DIM, out, DIM, DIM, bo);
}

// Round 12
// 423.272 us; speedup vs baseline: 2.3211x; 1.3557x over previous
//
#include <hip/hip_runtime.h>
#include <hip/hip_bf16.h>
#include <math.h>

#define DEV_INLINE __device__ __forceinline__

typedef float f32x4 __attribute__((ext_vector_type(4)));
typedef short bf16x8 __attribute__((ext_vector_type(8)));
typedef short s16x4 __attribute__((ext_vector_type(4)));

constexpr int B_    = 4;
constexpr int QLEN  = 512;
constexpr int KLEN  = 1024;
constexpr int DIM   = 512;
constexpr int H_MA  = 4;
constexpr int H_CA  = 2;
constexpr int CHUNK = 4;
constexpr float EPS = 1e-6f;
constexpr float INV_SCALE = 1.0f / 22.62741699796952f;  // 1/sqrt(512)

// ---------------------------------------------------------------------------
// fp32 -> bf16 hi/lo split (RNE both halves; a ~= hi + lo, rel err ~2^-17)
// ---------------------------------------------------------------------------

DEV_INLINE unsigned short f2bf(float x) {
    unsigned int u = __float_as_uint(x);
    unsigned int r = u + 0x7FFFu + ((u >> 16) & 1u);
    return (unsigned short)(r >> 16);
}

DEV_INLINE void split2(float x, short& h, short& l) {
    const unsigned short hb = f2bf(x);
    const float hf = __uint_as_float(((unsigned int)hb) << 16);
    h = (short)hb;
    l = (short)f2bf(x - hf);
}

// X[M,512] fp32 -> Xh, Xl bf16 row-major
__global__ __launch_bounds__(256) void rowsplit_kernel(
    const float* __restrict__ X, short* __restrict__ Xh,
    short* __restrict__ Xl, int n4)
{
    const int i = blockIdx.x * 256 + threadIdx.x;
    if (i >= n4) return;
    const f32x4 v = *(const f32x4*)(X + (size_t)i * 4);
    s16x4 h, l;
#pragma unroll
    for (int j = 0; j < 4; ++j) {
        short hh, ll;
        split2(v[j], hh, ll);
        h[j] = hh; l[j] = ll;
    }
    *(s16x4*)(Xh + (size_t)i * 4) = h;
    *(s16x4*)(Xl + (size_t)i * 4) = l;
}

// W[512,512] fp32 -> WTh, WTl [N,K] bf16 (transposed)
__global__ __launch_bounds__(256) void transsplit_kernel(
    const float* __restrict__ W, short* __restrict__ WTh,
    short* __restrict__ WTl)
{
    __shared__ __align__(16) short Th[64][72];
    __shared__ __align__(16) short Tl[64][72];
    const int t = threadIdx.x;
    const int k0 = blockIdx.x * 64;
    const int n0 = blockIdx.y * 64;
#pragma unroll
    for (int i = 0; i < 4; ++i) {
        const int c  = t + 256 * i;
        const int kr = c >> 4;
        const int nc = c & 15;
        const f32x4 v = *(const f32x4*)(W + (size_t)(k0 + kr) * DIM + n0 + nc * 4);
#pragma unroll
        for (int j = 0; j < 4; ++j) {
            short h, l;
            split2(v[j], h, l);
            Th[nc * 4 + j][kr] = h;
            Tl[nc * 4 + j][kr] = l;
        }
    }
    __syncthreads();
#pragma unroll
    for (int i = 0; i < 4; ++i) {
        const int c  = t + 256 * i;
        const int nr = c >> 4;
        const int kc = c & 15;
        *(s16x4*)(WTh + (size_t)(n0 + nr) * DIM + k0 + kc * 4) = *(const s16x4*)&Th[nr][kc * 4];
        *(s16x4*)(WTl + (size_t)(n0 + nr) * DIM + k0 + kc * 4) = *(const s16x4*)&Tl[nr][kc * 4];
    }
}

// ---------------------------------------------------------------------------
// split-bf16 MFMA NT GEMM core: C[64,64] = (Ah+Al)[M,K] @ (Bh+Bl)[N,K]^T
// 256 thr = 4 waves; wave (wm,wn) owns 32x32; frags 16x16x32 bf16.
// A frag: lane l holds A[m=l&15][k=(l>>4)*8 + i]; B frag: B[n=l&15][k=...].
// D frag: D[m=(l>>4)*4+j][n=l&15]  (m89-verified layout).
// ---------------------------------------------------------------------------

DEV_INLINE void mfma_nt_core(const short* __restrict__ Ah, const short* __restrict__ Al, int lda,
                             const short* __restrict__ Bh, const short* __restrict__ Bl, int ldb,
                             int K, int bm, int bn, f32x4 (&acc)[2][2])
{
    __shared__ __align__(16) short AsH[4][4][16][8];
    __shared__ __align__(16) short AsL[4][4][16][8];
    __shared__ __align__(16) short BsH[4][4][16][8];
    __shared__ __align__(16) short BsL[4][4][16][8];
    const int tid  = threadIdx.x;
    const int lane = tid & 63;
    const int w    = tid >> 6;
    const int wm   = w >> 1, wn = w & 1;
    const int r    = tid >> 2;      // 0..63 staging row
    const int kg   = tid & 3;       // 0..3 k-group
    const int rb   = r >> 4, rr = r & 15;
    const int lkg  = lane >> 4, lrr = lane & 15;

    for (int k0 = 0; k0 < K; k0 += 32) {
        const bf16x8 avh = *(const bf16x8*)(Ah + (size_t)(bm + r) * lda + k0 + kg * 8);
        const bf16x8 avl = *(const bf16x8*)(Al + (size_t)(bm + r) * lda + k0 + kg * 8);
        const bf16x8 bvh = *(const bf16x8*)(Bh + (size_t)(bn + r) * ldb + k0 + kg * 8);
        const bf16x8 bvl = *(const bf16x8*)(Bl + (size_t)(bn + r) * ldb + k0 + kg * 8);
        __syncthreads();
        *(bf16x8*)&AsH[rb][kg][rr][0] = avh;
        *(bf16x8*)&AsL[rb][kg][rr][0] = avl;
        *(bf16x8*)&BsH[rb][kg][rr][0] = bvh;
        *(bf16x8*)&BsL[rb][kg][rr][0] = bvl;
        __syncthreads();
#pragma unroll
        for (int fm = 0; fm < 2; ++fm) {
            const bf16x8 ah = *(const bf16x8*)&AsH[wm * 2 + fm][lkg][lrr][0];
            const bf16x8 al = *(const bf16x8*)&AsL[wm * 2 + fm][lkg][lrr][0];
#pragma unroll
            for (int fn = 0; fn < 2; ++fn) {
                const bf16x8 bh = *(const bf16x8*)&BsH[wn * 2 + fn][lkg][lrr][0];
                const bf16x8 bl = *(const bf16x8*)&BsL[wn * 2 + fn][lkg][lrr][0];
                acc[fm][fn] = __builtin_amdgcn_mfma_f32_16x16x32_bf16(ah, bh, acc[fm][fn], 0, 0, 0);
                acc[fm][fn] = __builtin_amdgcn_mfma_f32_16x16x32_bf16(ah, bl, acc[fm][fn], 0, 0, 0);
                acc[fm][fn] = __builtin_amdgcn_mfma_f32_16x16x32_bf16(al, bh, acc[fm][fn], 0, 0, 0);
            }
        }
    }
}

// fp32 output: C = acc*scale + (radd?*radd:0) + (bias?bias[col]:0)
__global__ __launch_bounds__(256) void mfma_nt_f32_kernel(
    const short* __restrict__ Ah, const short* __restrict__ Al, int lda,
    const short* __restrict__ Bh, const short* __restrict__ Bl, int ldb,
    float* __restrict__ C, int ldc, int K,
    const float* __restrict__ bias, const float* __restrict__ radd, float scale)
{
    f32x4 acc[2][2] = {};
    const int bm = blockIdx.x * 64, bn = blockIdx.y * 64;
    mfma_nt_core(Ah, Al, lda, Bh, Bl, ldb, K, bm, bn, acc);
    const int lane = threadIdx.x & 63;
    const int w = threadIdx.x >> 6;
    const int wm = w >> 1, wn = w & 1;
    const float addv = radd ? radd[0] : 0.0f;
#pragma unroll
    for (int fm = 0; fm < 2; ++fm)
#pragma unroll
        for (int fn = 0; fn < 2; ++fn) {
            const int col = bn + wn * 32 + fn * 16 + (lane & 15);
            const float bv = bias ? bias[col] : 0.0f;
#pragma unroll
            for (int j = 0; j < 4; ++j) {
                const int row = bm + wm * 32 + fm * 16 + (lane >> 4) * 4 + j;
                C[(size_t)row * ldc + col] = acc[fm][fn][j] * scale + addv + bv;
            }
        }
}

// bf16-pair output (for projection outputs feeding energy GEMMs)
__global__ __launch_bounds__(256) void mfma_nt_bf16_kernel(
    const short* __restrict__ Ah, const short* __restrict__ Al, int lda,
    const short* __restrict__ Bh, const short* __restrict__ Bl, int ldb,
    short* __restrict__ Ch, short* __restrict__ Cl, int ldc, int K,
    const float* __restrict__ bias)
{
    f32x4 acc[2][2] = {};
    const int bm = blockIdx.x * 64, bn = blockIdx.y * 64;
    mfma_nt_core(Ah, Al, lda, Bh, Bl, ldb, K, bm, bn, acc);
    const int lane = threadIdx.x & 63;
    const int w = threadIdx.x >> 6;
    const int wm = w >> 1, wn = w & 1;
#pragma unroll
    for (int fm = 0; fm < 2; ++fm)
#pragma unroll
        for (int fn = 0; fn < 2; ++fn) {
            const int col = bn + wn * 32 + fn * 16 + (lane & 15);
            const float bv = bias ? bias[col] : 0.0f;
#pragma unroll
            for (int j = 0; j < 4; ++j) {
                const int row = bm + wm * 32 + fm * 16 + (lane >> 4) * 4 + j;
                short h, l;
                split2(acc[fm][fn][j] + bv, h, l);
                Ch[(size_t)row * ldc + col] = h;
                Cl[(size_t)row * ldc + col] = l;
            }
        }
}

// energy: E[z,q,k] = (QP[q,:].KP[k,:]) * INV_SCALE + (radd?*radd:0), per head
__global__ __launch_bounds__(256) void energy_mfma_kernel(
    const short* __restrict__ QPh, const short* __restrict__ QPl,
    const short* __restrict__ KPh, const short* __restrict__ KPl,
    float* __restrict__ E, int H, int HD, const float* __restrict__ radd)
{
    const int z = blockIdx.z;
    const int b = z / H;
    const int h = z - b * H;
    const short* Ah = QPh + (size_t)b * QLEN * DIM + h * HD;
    const short* Al = QPl + (size_t)b * QLEN * DIM + h * HD;
    const short* Bh = KPh + (size_t)b * KLEN * DIM + h * HD;
    const short* Bl = KPl + (size_t)b * KLEN * DIM + h * HD;
    float* C = E + (size_t)z * QLEN * KLEN;

    f32x4 acc[2][2] = {};
    const int bm = blockIdx.x * 64, bn = blockIdx.y * 64;
    mfma_nt_core(Ah, Al, DIM, Bh, Bl, DIM, HD, bm, bn, acc);
    const int lane = threadIdx.x & 63;
    const int w = threadIdx.x >> 6;
    const int wm = w >> 1, wn = w & 1;
    const float addv = radd ? radd[0] : 0.0f;
#pragma unroll
    for (int fm = 0; fm < 2; ++fm)
#pragma unroll
        for (int fn = 0; fn < 2; ++fn) {
            const int col = bn + wn * 32 + fn * 16 + (lane & 15);
#pragma unroll
            for (int j = 0; j < 4; ++j) {
                const int row = bm + wm * 32 + fm * 16 + (lane >> 4) * 4 + j;
                C[(size_t)row * KLEN + col] = acc[fm][fn][j] * INV_SCALE + addv;
            }
        }
}

// ---------------------------------------------------------------------------
// row transforms (unchanged, round-8 verified)
// ---------------------------------------------------------------------------

__global__ __launch_bounds__(256) void ma_row_kernel(float* __restrict__ PCP,
                                                     float* __restrict__ ICP)
{
    const size_t row = blockIdx.x;
    float* pe = PCP + row * KLEN;
    float* pi = ICP + row * KLEN;
    const int tid = threadIdx.x;
    const int lane = tid & 63, wid = tid >> 6;

    const float4 ev = *(const float4*)(pe + tid * 4);
    float e[4] = {ev.x, ev.y, ev.z, ev.w};
    float p[4], l[4], s[4];
    float run = 0.0f;
#pragma unroll
    for (int j = 0; j < 4; ++j) {
        p[j] = 1.0f / (1.0f + expf(-e[j]));
        float om = 1.0f - p[j];
        om = fminf(fmaxf(om, EPS), 1.0f);
        l[j] = logf(om);
        run += l[j];
        s[j] = run;
    }
    const float t = run;
    float v = t;
#pragma unroll
    for (int off = 1; off < 64; off <<= 1) {
        const float u = __shfl_up(v, off);
        if (lane >= off) v += u;
    }
    __shared__ float wsum[4];
    if (lane == 63) wsum[wid] = v;
    __syncthreads();
    float base = v - t;
    for (int w = 0; w < wid; ++w) base += wsum[w];

    float4 po, io;
    float* pp = (float*)&po;
    float* ip = (float*)&io;
#pragma unroll
    for (int j = 0; j < 4; ++j) {
        const float cum = base + s[j];
        const float cp  = expf(cum - l[j]);
        pp[j] = p[j] * cp;
        ip[j] = 1.0f / fmaxf(cp, EPS);
    }
    *(float4*)(pe + tid * 4) = po;
    *(float4*)(pi + tid * 4) = io;
}

__global__ __launch_bounds__(256) void ca_row_kernel(float* __restrict__ SE,
                                                     float* __restrict__ DEN)
{
    const size_t row = blockIdx.x;
    float* ps = SE + row * KLEN;
    float* pd = DEN + row * KLEN;
    const int tid = threadIdx.x;
    const int lane = tid & 63, wid = tid >> 6;

    const float4 ev = *(const float4*)(ps + tid * 4);
    float e[4] = {ev.x, ev.y, ev.z, ev.w};
    float m = fmaxf(fmaxf(e[0], e[1]), fmaxf(e[2], e[3]));
#pragma unroll
    for (int off = 32; off >= 1; off >>= 1)
        m = fmaxf(m, __shfl_xor(m, off));
    __shared__ float wmax[4];
    if (lane == 0) wmax[wid] = m;
    __syncthreads();
    m = fmaxf(fmaxf(wmax[0], wmax[1]), fmaxf(wmax[2], wmax[3]));

    __shared__ float sh[KLEN + 3];
    if (tid < 3) sh[tid] = 0.0f;
    float se[4];
#pragma unroll
    for (int j = 0; j < 4; ++j) {
        se[j] = fmaxf(expf(e[j] - m), 1e-5f);
        sh[3 + tid * 4 + j] = se[j];
    }
    __syncthreads();
    float4 so, do_;
    float* sp = (float*)&so;
    float* dp = (float*)&do_;
#pragma unroll
    for (int j = 0; j < 4; ++j) {
        const int k = tid * 4 + j;
        sp[j] = se[j];
        dp[j] = sh[3 + k] + sh[2 + k] + sh[1 + k] + sh[k];
    }
    *(float4*)(ps + tid * 4) = so;
    *(float4*)(pd + tid * 4) = do_;
}

// ---------------------------------------------------------------------------
// alpha recurrence (ROUND-8 VERSION, verified): single wave per (b,h_ma),
// DPP wave scan, 8-deep LDS ring via global_load_lds, counted vmcnt.
// ---------------------------------------------------------------------------

template<int CTRL, int ROW_MASK>
DEV_INLINE float dpp_add(float x) {
    int t = __builtin_amdgcn_update_dpp(0, __float_as_int(x), CTRL, ROW_MASK, 0xf, true);
    return x + __int_as_float(t);
}

DEV_INLINE float wave64_incl_scan(float x) {
    x = dpp_add<0x111, 0xf>(x);
    x = dpp_add<0x112, 0xf>(x);
    x = dpp_add<0x114, 0xf>(x);
    x = dpp_add<0x118, 0xf>(x);
    x = dpp_add<0x142, 0xa>(x);
    x = dpp_add<0x143, 0xc>(x);
    return x;
}

typedef __attribute__((address_space(3))) void lv_t;
typedef __attribute__((address_space(1))) const void gv_t;

DEV_INLINE void dma16(const float* g, float* l) {
    __builtin_amdgcn_global_load_lds((gv_t*)g, (lv_t*)l, 16, 0, 0);
}

template<int N> DEV_INLINE void vwait() {
    asm volatile("s_waitcnt vmcnt(%0)" :: "i"(N) : "memory");
    __builtin_amdgcn_sched_barrier(0);
}

DEV_INLINE void alpha_step(const f32x4& P0, const f32x4& P1,
                           const f32x4& P2, const f32x4& P3,
                           const f32x4& I0, const f32x4& I1,
                           const f32x4& I2, const f32x4& I3,
                           float (&a)[16])
{
    float pc[16], ic[16];
    *(f32x4*)&pc[0] = P0; *(f32x4*)&pc[4] = P1;
    *(f32x4*)&pc[8] = P2; *(f32x4*)&pc[12] = P3;
    *(f32x4*)&ic[0] = I0; *(f32x4*)&ic[4] = I1;
    *(f32x4*)&ic[8] = I2; *(f32x4*)&ic[12] = I3;

    float t[16];
#pragma unroll
    for (int j = 0; j < 16; ++j) t[j] = a[j] * ic[j];

    float u1[8], u2[4];
#pragma unroll
    for (int j = 0; j < 8; ++j) u1[j] = t[2 * j] + t[2 * j + 1];
#pragma unroll
    for (int j = 0; j < 4; ++j) u2[j] = u1[2 * j] + u1[2 * j + 1];
    const float tot = (u2[0] + u2[1]) + (u2[2] + u2[3]);

    const float incl = wave64_incl_scan(tot);
    const float excl = incl - tot;

    float s = 0.0f;
#pragma unroll
    for (int j = 0; j < 16; ++j) {
        s += t[j];
        a[j] = pc[j] * (excl + s);
    }
}

#define DMA_ROW(b, prow, irow)                        \
    dma16((prow) + 0,  &ring[b][0][0]);               \
    dma16((prow) + 4,  &ring[b][0][256]);             \
    dma16((prow) + 8,  &ring[b][0][512]);             \
    dma16((prow) + 12, &ring[b][0][768]);             \
    dma16((irow) + 0,  &ring[b][1][0]);               \
    dma16((irow) + 4,  &ring[b][1][256]);             \
    dma16((irow) + 8,  &ring[b][1][512]);             \
    dma16((irow) + 12, &ring[b][1][768]);

#define READ_ROW(b, G)                                   \
    p##G##0 = *(const f32x4*)&ring[b][0][0   + l4];      \
    p##G##1 = *(const f32x4*)&ring[b][0][256 + l4];      \
    p##G##2 = *(const f32x4*)&ring[b][0][512 + l4];      \
    p##G##3 = *(const f32x4*)&ring[b][0][768 + l4];      \
    i##G##0 = *(const f32x4*)&ring[b][1][0   + l4];      \
    i##G##1 = *(const f32x4*)&ring[b][1][256 + l4];      \
    i##G##2 = *(const f32x4*)&ring[b][1][512 + l4];      \
    i##G##3 = *(const f32x4*)&ring[b][1][768 + l4];

#define STEP(WAITN, BUFC, BUFN, DO_READ, DO_DMA, CG, NG)              \
    {                                                                 \
        vwait<WAITN>();                                               \
        if (DO_READ) { READ_ROW(BUFN, NG) }                           \
        alpha_step(p##CG##0, p##CG##1, p##CG##2, p##CG##3,            \
                   i##CG##0, i##CG##1, i##CG##2, i##CG##3, a);        \
        *(f32x4*)(st + 0)  = *(const f32x4*)&a[0];                    \
        *(f32x4*)(st + 4)  = *(const f32x4*)&a[4];                    \
        *(f32x4*)(st + 8)  = *(const f32x4*)&a[8];                    \
        *(f32x4*)(st + 12) = *(const f32x4*)&a[12];                   \
        st += KLEN;                                                   \
        if (DO_DMA) {                                                 \
            __builtin_amdgcn_sched_barrier(0);                        \
            DMA_ROW(BUFC, np, ni)                                     \
            np += KLEN; ni += KLEN;                                   \
        }                                                             \
    }

__global__ __launch_bounds__(64) void alpha_kernel(float* __restrict__ PCP,
                                                   const float* __restrict__ ICP)
{
    __shared__ float ring[8][2][1024];   // 64 KB

    const int z = blockIdx.x;
    float* base = PCP + (size_t)z * QLEN * KLEN;
    const float* ibase = ICP + (size_t)z * QLEN * KLEN;
    const int lane = threadIdx.x;
    const int col = lane * 16;
    const int l4 = lane * 4;

    {
        const float* pp = base + col;
        const float* ip = ibase + col;
        DMA_ROW(0, pp, ip) pp += KLEN; ip += KLEN;
        DMA_ROW(1, pp, ip) pp += KLEN; ip += KLEN;
        DMA_ROW(2, pp, ip) pp += KLEN; ip += KLEN;
        DMA_ROW(3, pp, ip) pp += KLEN; ip += KLEN;
        DMA_ROW(4, pp, ip) pp += KLEN; ip += KLEN;
        DMA_ROW(5, pp, ip) pp += KLEN; ip += KLEN;
        DMA_ROW(6, pp, ip) pp += KLEN; ip += KLEN;
        DMA_ROW(7, pp, ip)
    }

    f32x4 pA0, pA1, pA2, pA3, iA0, iA1, iA2, iA3;
    f32x4 pB0, pB1, pB2, pB3, iB0, iB1, iB2, iB3;

    vwait<56>();
    READ_ROW(0, A)

    float a[16];
#pragma unroll
    for (int j = 0; j < 16; ++j) a[j] = 0.0f;
    if (lane == 0) a[0] = 1.0f;

    float* st = base + col;
    const float* np = base + (size_t)8 * KLEN + col;
    const float* ni = ibase + (size_t)8 * KLEN + col;

    for (int it = 0; it < 63; ++it) {
        STEP(48, 0, 1, true, true, A, B)
        STEP(48, 1, 2, true, true, B, A)
        STEP(48, 2, 3, true, true, A, B)
        STEP(48, 3, 4, true, true, B, A)
        STEP(48, 4, 5, true, true, A, B)
        STEP(48, 5, 6, true, true, B, A)
        STEP(48, 6, 7, true, true, A, B)
        STEP(48, 7, 0, true, true, B, A)
    }

    STEP(48, 0, 1, true, false, A, B)
    STEP(40, 1, 2, true, false, B, A)
    STEP(32, 2, 3, true, false, A, B)
    STEP(24, 3, 4, true, false, B, A)
    STEP(16, 4, 5, true, false, A, B)
    STEP(8,  5, 6, true, false, B, A)
    STEP(0,  6, 7, true, false, A, B)
    STEP(0,  7, 0, false, false, B, A)
}

// ---------------------------------------------------------------------------
// fused beta+cv (round-11 verified) + bf16-pair CV epilogue for MFMA out-proj
// ---------------------------------------------------------------------------

__global__ __launch_bounds__(256) void fused_cv_kernel(
    const float* __restrict__ ALPHA, const float* __restrict__ SE,
    const float* __restrict__ DEN, const float* __restrict__ VP,
    float* __restrict__ CV, short* __restrict__ CVh, short* __restrict__ CVl)
{
    const int z = blockIdx.y;          // b*8 + hma*2 + hca
    const int b = z >> 3;
    const int h = z & 7;
    const int hma = h >> 1;
    const int hca = h & 1;
    const int bm = blockIdx.x * 64;

    const float* a_base  = ALPHA + ((size_t)b * H_MA + hma) * QLEN * KLEN;
    const float* se_base = SE  + ((size_t)b * H_CA + hca) * QLEN * KLEN;
    const float* dn_base = DEN + ((size_t)b * H_CA + hca) * QLEN * KLEN;
    const float* Bm = VP + (size_t)b * KLEN * DIM + h * 64;
    float* C  = CV  + (size_t)b * QLEN * DIM + h * 64;
    short* Ch = CVh + (size_t)b * QLEN * DIM + h * 64;
    short* Cl = CVl + (size_t)b * QLEN * DIM + h * 64;

    __shared__ float As[16][68];
    __shared__ float Bs[16][68];
    const int tid  = threadIdx.x;
    const int tm   = (tid >> 4) << 2;
    const int tn   = (tid & 15) << 2;
    const int arow = tid >> 2;
    const int acol = (tid & 3) << 2;
    const int brow = tid >> 4;
    const int bcol = (tid & 15) << 2;
    float acc[4][4] = {};

    for (int k0 = 0; k0 < KLEN; k0 += 16) {
        const int ka = k0 + acol;
        const size_t roff = (size_t)(bm + arow) * KLEN;
        const f32x4 sev = *(const f32x4*)(se_base + roff + ka);
        const f32x4 al0 = *(const f32x4*)(a_base + roff + ka);
        const f32x4 dn0 = *(const f32x4*)(dn_base + roff + ka);
        f32x4 al1 = {0.0f, 0.0f, 0.0f, 0.0f};
        f32x4 dn1 = {1.0f, 1.0f, 1.0f, 1.0f};
        if (ka + 4 < KLEN) {
            al1 = *(const f32x4*)(a_base + roff + ka + 4);
            dn1 = *(const f32x4*)(dn_base + roff + ka + 4);
        }
        float ad[7];
#pragma unroll
        for (int j = 0; j < 4; ++j) ad[j] = al0[j] / dn0[j];
#pragma unroll
        for (int j = 0; j < 3; ++j) ad[4 + j] = al1[j] / dn1[j];
        const float4 bv = *(const float4*)(Bm + (size_t)(k0 + brow) * DIM + bcol);
        __syncthreads();
        As[acol + 0][arow] = sev[0] * (ad[0] + ad[1] + ad[2] + ad[3]);
        As[acol + 1][arow] = sev[1] * (ad[1] + ad[2] + ad[3] + ad[4]);
        As[acol + 2][arow] = sev[2] * (ad[2] + ad[3] + ad[4] + ad[5]);
        As[acol + 3][arow] = sev[3] * (ad[3] + ad[4] + ad[5] + ad[6]);
        *(float4*)(&Bs[brow][bcol]) = bv;
        __syncthreads();
#pragma unroll
        for (int kk = 0; kk < 16; ++kk) {
            const float4 av = *(const float4*)&As[kk][tm];
            const float4 bw = *(const float4*)&Bs[kk][tn];
            const float ar[4] = {av.x, av.y, av.z, av.w};
            const float br[4] = {bw.x, bw.y, bw.z, bw.w};
#pragma unroll
            for (int i = 0; i < 4; ++i)
#pragma unroll
                for (int j = 0; j < 4; ++j)
                    acc[i][j] = fmaf(ar[i], br[j], acc[i][j]);
        }
    }
#pragma unroll
    for (int i = 0; i < 4; ++i) {
        float4 o;
        float* op = (float*)&o;
        s16x4 oh, ol;
#pragma unroll
        for (int j = 0; j < 4; ++j) {
            op[j] = acc[i][j];
            short hh, ll;
            split2(op[j], hh, ll);
            oh[j] = hh; ol[j] = ll;
        }
        const size_t ro = (size_t)(bm + tm + i) * DIM + tn;
        *(float4*)(C + ro) = o;
        *(s16x4*)(Ch + ro) = oh;
        *(s16x4*)(Cl + ro) = ol;
    }
}

// ---------------------------------------------------------------------------

extern "C" void kernel_launch(void* const* d_in, const int* in_sizes, int n_in,
                              void* d_out, int out_size, void* d_ws, size_t ws_size,
                              hipStream_t stream)
{
    (void)in_sizes; (void)n_in; (void)out_size; (void)ws_size;
    const float* key_t = (const float*)d_in[0];
    const float* query = (const float*)d_in[1];
    const float* wk_ma = (const float*)d_in[2];
    const float* bk_ma = (const float*)d_in[3];
    const float* wq_ma = (const float*)d_in[4];
    const float* bq_ma = (const float*)d_in[5];
    const float* r     = (const float*)d_in[6];
    const float* wk_ca = (const float*)d_in[7];
    const float* bk_ca = (const float*)d_in[8];
    const float* wq_ca = (const float*)d_in[9];
    const float* bq_ca = (const float*)d_in[10];
    const float* wv    = (const float*)d_in[11];
    const float* bv    = (const float*)d_in[12];
    const float* wo    = (const float*)d_in[13];
    const float* bo    = (const float*)d_in[14];
    float* out = (float*)d_out;

    // ---- workspace layout (bytes). Total ~131.2 MB.
    char* w8 = (char*)d_ws;
    float* PCP  = (float*)(w8);                        // 32 MB (e_ma->pcp->alpha)
    float* ICP  = (float*)(w8 + (32ull << 20));        // 32 MB
    float* SE   = (float*)(w8 + (64ull << 20));        // 16 MB (e_ca->se)
    float* VP   = (float*)(w8 + (80ull << 20));        //  8 MB fp32
    short* keyh = (short*)(w8 + (88ull << 20));        //  4 MB
    short* keyl = (short*)(w8 + (92ull << 20));
    short* qh   = (short*)(w8 + (96ull << 20));        //  2 MB
    short* ql   = (short*)(w8 + (98ull << 20));
    short* WT   = (short*)(w8 + (100ull << 20));       //  6 MB: 6 mats x (h,l)
    const size_t WSZ = 512 * 512;
    short* wkmaT_h = WT + 0 * 2 * WSZ;  short* wkmaT_l = wkmaT_h + WSZ;
    short* wqmaT_h = WT + 1 * 2 * WSZ;  short* wqmaT_l = wqmaT_h + WSZ;
    short* wkcaT_h = WT + 2 * 2 * WSZ;  short* wkcaT_l = wkcaT_h + WSZ;
    short* wqcaT_h = WT + 3 * 2 * WSZ;  short* wqcaT_l = wqcaT_h + WSZ;
    short* wvT_h   = WT + 4 * 2 * WSZ;  short* wvT_l   = wvT_h + WSZ;
    short* woT_h   = WT + 5 * 2 * WSZ;  short* woT_l   = woT_h + WSZ;
    short* PRJ  = (short*)(w8 + (106ull << 20));       // 25.2 MB proj outs
    const size_t KPSZ = (size_t)B_ * KLEN * DIM;       // 2,097,152
    const size_t QPSZ = (size_t)B_ * QLEN * DIM;       // 1,048,576
    short* KPMAh = PRJ;                 short* KPMAl = KPMAh + KPSZ;
    short* QPMAh = KPMAl + KPSZ;        short* QPMAl = QPMAh + QPSZ;
    short* KPCAh = QPMAl + QPSZ;        short* KPCAl = KPCAh + KPSZ;
    short* QPCAh = KPCAl + KPSZ;        short* QPCAl = QPCAh + QPSZ;
    // overlays (dead after energies): DEN over first 16 MB of PRJ; CV over rest
    float* DEN = (float*)(w8 + (106ull << 20));        // 16 MB
    float* CV  = (float*)(w8 + (122ull << 20));        //  4 MB
    short* CVh = (short*)(w8 + (126ull << 20));        //  2 MB
    short* CVl = (short*)(w8 + (128ull << 20));        //  2 MB

    const dim3 blk(256);

    // 1) fp32 -> bf16 pair conversions
    rowsplit_kernel<<<dim3((KPSZ / 4 + 255) / 256), blk, 0, stream>>>(key_t, keyh, keyl, (int)(KPSZ / 4));
    rowsplit_kernel<<<dim3((QPSZ / 4 + 255) / 256), blk, 0, stream>>>(query, qh, ql, (int)(QPSZ / 4));
    transsplit_kernel<<<dim3(8, 8), blk, 0, stream>>>(wk_ma, wkmaT_h, wkmaT_l);
    transsplit_kernel<<<dim3(8, 8), blk, 0, stream>>>(wq_ma, wqmaT_h, wqmaT_l);
    transsplit_kernel<<<dim3(8, 8), blk, 0, stream>>>(wk_ca, wkcaT_h, wkcaT_l);
    transsplit_kernel<<<dim3(8, 8), blk, 0, stream>>>(wq_ca, wqcaT_h, wqcaT_l);
    transsplit_kernel<<<dim3(8, 8), blk, 0, stream>>>(wv, wvT_h, wvT_l);
    transsplit_kernel<<<dim3(8, 8), blk, 0, stream>>>(wo, woT_h, woT_l);

    // 2) projections (split-bf16 MFMA NT; bf16-pair outputs for energies)
    mfma_nt_bf16_kernel<<<dim3(B_ * KLEN / 64, DIM / 64), blk, 0, stream>>>(
        keyh, keyl, DIM, wkmaT_h, wkmaT_l, DIM, KPMAh, KPMAl, DIM, DIM, bk_ma);
    mfma_nt_bf16_kernel<<<dim3(B_ * QLEN / 64, DIM / 64), blk, 0, stream>>>(
        qh, ql, DIM, wqmaT_h, wqmaT_l, DIM, QPMAh, QPMAl, DIM, DIM, bq_ma);
    mfma_nt_bf16_kernel<<<dim3(B_ * KLEN / 64, DIM / 64), blk, 0, stream>>>(
        keyh, keyl, DIM, wkcaT_h, wkcaT_l, DIM, KPCAh, KPCAl, DIM, DIM, bk_ca);
    mfma_nt_bf16_kernel<<<dim3(B_ * QLEN / 64, DIM / 64), blk, 0, stream>>>(
        qh, ql, DIM, wqcaT_h, wqcaT_l, DIM, QPCAh, QPCAl, DIM, DIM, bq_ca);
    mfma_nt_f32_kernel<<<dim3(B_ * KLEN / 64, DIM / 64), blk, 0, stream>>>(
        keyh, keyl, DIM, wvT_h, wvT_l, DIM, VP, DIM, DIM, bv, nullptr, 1.0f);

    // 3) energies (split-bf16 MFMA NT, batched over (b,h))
    energy_mfma_kernel<<<dim3(QLEN / 64, KLEN / 64, B_ * H_MA), blk, 0, stream>>>(
        QPMAh, QPMAl, KPMAh, KPMAl, PCP, H_MA, DIM / H_MA, r);
    energy_mfma_kernel<<<dim3(QLEN / 64, KLEN / 64, B_ * H_CA), blk, 0, stream>>>(
        QPCAh, QPCAl, KPCAh, KPCAl, SE, H_CA, DIM / H_CA, nullptr);

    // 4) row transforms (DEN overlays dead proj-out region — written here)
    ma_row_kernel<<<dim3(B_ * H_MA * QLEN), blk, 0, stream>>>(PCP, ICP);
    ca_row_kernel<<<dim3(B_ * H_CA * QLEN), blk, 0, stream>>>(SE, DEN);

    // 5) monotonic alignment recurrence (round-8 LDS-ring version)
    alpha_kernel<<<dim3(B_ * H_MA), dim3(64), 0, stream>>>(PCP, ICP);

    // 6) fused beta+cv (also emits CV bf16 pair)
    fused_cv_kernel<<<dim3(QLEN / 64, B_ * H_MA * H_CA), blk, 0, stream>>>(
        PCP, SE, DEN, VP, CV, CVh, CVl);

    // 7) output projection (split-bf16 MFMA)
    mfma_nt_f32_kernel<<<dim3(B_ * QLEN / 64, DIM / 64), blk, 0, stream>>>(
        CVh, CVl, DIM, woT_h, woT_l, DIM, out, DIM, DIM, bo, nullptr, 1.0f);
}

// Round 13
// 411.470 us; speedup vs baseline: 2.3877x; 1.0287x over previous
//
#include <hip/hip_runtime.h>
#include <hip/hip_bf16.h>
#include <math.h>

#define DEV_INLINE __device__ __forceinline__

typedef float f32x4 __attribute__((ext_vector_type(4)));
typedef short bf16x8 __attribute__((ext_vector_type(8)));
typedef short s16x4 __attribute__((ext_vector_type(4)));

constexpr int B_    = 4;
constexpr int QLEN  = 512;
constexpr int KLEN  = 1024;
constexpr int DIM   = 512;
constexpr int H_MA  = 4;
constexpr int H_CA  = 2;
constexpr int CHUNK = 4;
constexpr float EPS = 1e-6f;
constexpr float INV_SCALE = 1.0f / 22.62741699796952f;  // 1/sqrt(512)

// ---------------------------------------------------------------------------
// fp32 -> bf16 hi/lo split (RNE both halves; a ~= hi + lo)
// ---------------------------------------------------------------------------

DEV_INLINE unsigned short f2bf(float x) {
    unsigned int u = __float_as_uint(x);
    unsigned int r = u + 0x7FFFu + ((u >> 16) & 1u);
    return (unsigned short)(r >> 16);
}

DEV_INLINE void split2(float x, short& h, short& l) {
    const unsigned short hb = f2bf(x);
    const float hf = __uint_as_float(((unsigned int)hb) << 16);
    h = (short)hb;
    l = (short)f2bf(x - hf);
}

DEV_INLINE float bf2f(short s) {
    return __uint_as_float(((unsigned int)(unsigned short)s) << 16);
}

__global__ __launch_bounds__(256) void rowsplit_kernel(
    const float* __restrict__ X, short* __restrict__ Xh,
    short* __restrict__ Xl, int n4)
{
    const int i = blockIdx.x * 256 + threadIdx.x;
    if (i >= n4) return;
    const f32x4 v = *(const f32x4*)(X + (size_t)i * 4);
    s16x4 h, l;
#pragma unroll
    for (int j = 0; j < 4; ++j) {
        short hh, ll;
        split2(v[j], hh, ll);
        h[j] = hh; l[j] = ll;
    }
    *(s16x4*)(Xh + (size_t)i * 4) = h;
    *(s16x4*)(Xl + (size_t)i * 4) = l;
}

// W[512,512] fp32 -> WTh, WTl [N,K]=[512,512] bf16 (transposed), ld 512
__global__ __launch_bounds__(256) void transsplit_kernel(
    const float* __restrict__ W, short* __restrict__ WTh,
    short* __restrict__ WTl)
{
    __shared__ __align__(16) short Th[64][72];
    __shared__ __align__(16) short Tl[64][72];
    const int t = threadIdx.x;
    const int k0 = blockIdx.x * 64;
    const int n0 = blockIdx.y * 64;
#pragma unroll
    for (int i = 0; i < 4; ++i) {
        const int c  = t + 256 * i;
        const int kr = c >> 4;
        const int nc = c & 15;
        const f32x4 v = *(const f32x4*)(W + (size_t)(k0 + kr) * DIM + n0 + nc * 4);
#pragma unroll
        for (int j = 0; j < 4; ++j) {
            short h, l;
            split2(v[j], h, l);
            Th[nc * 4 + j][kr] = h;
            Tl[nc * 4 + j][kr] = l;
        }
    }
    __syncthreads();
#pragma unroll
    for (int i = 0; i < 4; ++i) {
        const int c  = t + 256 * i;
        const int nr = c >> 4;
        const int kc = c & 15;
        *(s16x4*)(WTh + (size_t)(n0 + nr) * DIM + k0 + kc * 4) = *(const s16x4*)&Th[nr][kc * 4];
        *(s16x4*)(WTl + (size_t)(n0 + nr) * DIM + k0 + kc * 4) = *(const s16x4*)&Tl[nr][kc * 4];
    }
}

// ---------------------------------------------------------------------------
// 128x128 split-bf16 MFMA NT core: 4 waves (2x2), wave tile 64x64 = 4x4 frags
// of 16x16x32. Per K=32 per wave: 48 MFMA : 16 ds_read_b128 (3:1).
// Frag layouts identical to the round-12-verified 64^2 core.
// ---------------------------------------------------------------------------

DEV_INLINE void mfma128_nt_core(
    const short* __restrict__ Ah, const short* __restrict__ Al, int lda,
    const short* __restrict__ Bh, const short* __restrict__ Bl, int ldb,
    int K, int bm, int bn, f32x4 (&acc)[4][4])
{
    __shared__ __align__(16) short AsH[8][4][16][8];   // 8 KB each
    __shared__ __align__(16) short AsL[8][4][16][8];
    __shared__ __align__(16) short BsH[8][4][16][8];
    __shared__ __align__(16) short BsL[8][4][16][8];
    const int tid  = threadIdx.x;
    const int lane = tid & 63;
    const int w    = tid >> 6;
    const int wm   = w >> 1, wn = w & 1;
    const int lkg  = lane >> 4, lrow = lane & 15;

    for (int k0 = 0; k0 < K; k0 += 32) {
        bf16x8 vah[2], val[2], vbh[2], vbl[2];
#pragma unroll
        for (int p = 0; p < 2; ++p) {
            const int c = p * 256 + tid;
            const int row = c >> 2, kk = c & 3;
            const size_t ao = (size_t)(bm + row) * lda + k0 + kk * 8;
            const size_t bo = (size_t)(bn + row) * ldb + k0 + kk * 8;
            vah[p] = *(const bf16x8*)(Ah + ao);
            val[p] = *(const bf16x8*)(Al + ao);
            vbh[p] = *(const bf16x8*)(Bh + bo);
            vbl[p] = *(const bf16x8*)(Bl + bo);
        }
        __syncthreads();
#pragma unroll
        for (int p = 0; p < 2; ++p) {
            const int c = p * 256 + tid;
            const int row = c >> 2, kk = c & 3;
            const int fm = row >> 4, rr = row & 15;
            *(bf16x8*)&AsH[fm][kk][rr][0] = vah[p];
            *(bf16x8*)&AsL[fm][kk][rr][0] = val[p];
            *(bf16x8*)&BsH[fm][kk][rr][0] = vbh[p];
            *(bf16x8*)&BsL[fm][kk][rr][0] = vbl[p];
        }
        __syncthreads();

        bf16x8 bhf[4], blf[4];
#pragma unroll
        for (int fn = 0; fn < 4; ++fn) {
            bhf[fn] = *(const bf16x8*)&BsH[wn * 4 + fn][lkg][lrow][0];
            blf[fn] = *(const bf16x8*)&BsL[wn * 4 + fn][lkg][lrow][0];
        }
#pragma unroll
        for (int fm = 0; fm < 4; ++fm) {
            const bf16x8 ah = *(const bf16x8*)&AsH[wm * 4 + fm][lkg][lrow][0];
            const bf16x8 al = *(const bf16x8*)&AsL[wm * 4 + fm][lkg][lrow][0];
#pragma unroll
            for (int fn = 0; fn < 4; ++fn) {
                acc[fm][fn] = __builtin_amdgcn_mfma_f32_16x16x32_bf16(ah, bhf[fn], acc[fm][fn], 0, 0, 0);
                acc[fm][fn] = __builtin_amdgcn_mfma_f32_16x16x32_bf16(ah, blf[fn], acc[fm][fn], 0, 0, 0);
                acc[fm][fn] = __builtin_amdgcn_mfma_f32_16x16x32_bf16(al, bhf[fn], acc[fm][fn], 0, 0, 0);
            }
        }
    }
}

// fused projection: C[M,Nc] bf16-pair = A @ WT^T + bias(segmented by 512 cols)
__global__ __launch_bounds__(256) void proj128_kernel(
    const short* __restrict__ Ah, const short* __restrict__ Al, int lda,
    const short* __restrict__ Bh, const short* __restrict__ Bl, int ldb,
    short* __restrict__ Ch, short* __restrict__ Cl, int ldc, int K,
    const float* __restrict__ b0, const float* __restrict__ b1,
    const float* __restrict__ b2)
{
    f32x4 acc[4][4] = {};
    const int bm = blockIdx.x * 128, bn = blockIdx.y * 128;
    mfma128_nt_core(Ah, Al, lda, Bh, Bl, ldb, K, bm, bn, acc);
    const int lane = threadIdx.x & 63;
    const int w = threadIdx.x >> 6;
    const int wm = w >> 1, wn = w & 1;
#pragma unroll
    for (int fm = 0; fm < 4; ++fm)
#pragma unroll
        for (int fn = 0; fn < 4; ++fn) {
            const int col = bn + wn * 64 + fn * 16 + (lane & 15);
            const int seg = col >> 9, cs = col & 511;
            const float bvv = seg == 0 ? b0[cs] : (seg == 1 ? b1[cs] : b2[cs]);
#pragma unroll
            for (int j = 0; j < 4; ++j) {
                const int row = bm + wm * 64 + fm * 16 + (lane >> 4) * 4 + j;
                short h, l;
                split2(acc[fm][fn][j] + bvv, h, l);
                Ch[(size_t)row * ldc + col] = h;
                Cl[(size_t)row * ldc + col] = l;
            }
        }
}

// energy: E[z,q,k] = (QP[q,:] . KP[k,:]) * INV_SCALE + (radd?*radd:0)
__global__ __launch_bounds__(256) void energy128_kernel(
    const short* __restrict__ QPh, const short* __restrict__ QPl, int lda, int colA0,
    const short* __restrict__ KPh, const short* __restrict__ KPl, int ldb, int colB0,
    float* __restrict__ E, int H, int HD, const float* __restrict__ radd)
{
    const int z = blockIdx.z;
    const int b = z / H;
    const int h = z - b * H;
    const short* Ah = QPh + (size_t)b * QLEN * lda + colA0 + h * HD;
    const short* Al = QPl + (size_t)b * QLEN * lda + colA0 + h * HD;
    const short* Bh = KPh + (size_t)b * KLEN * ldb + colB0 + h * HD;
    const short* Bl = KPl + (size_t)b * KLEN * ldb + colB0 + h * HD;
    float* C = E + (size_t)z * QLEN * KLEN;

    f32x4 acc[4][4] = {};
    const int bm = blockIdx.x * 128, bn = blockIdx.y * 128;
    mfma128_nt_core(Ah, Al, lda, Bh, Bl, ldb, HD, bm, bn, acc);
    const int lane = threadIdx.x & 63;
    const int w = threadIdx.x >> 6;
    const int wm = w >> 1, wn = w & 1;
    const float addv = radd ? radd[0] : 0.0f;
#pragma unroll
    for (int fm = 0; fm < 4; ++fm)
#pragma unroll
        for (int fn = 0; fn < 4; ++fn) {
            const int col = bn + wn * 64 + fn * 16 + (lane & 15);
#pragma unroll
            for (int j = 0; j < 4; ++j) {
                const int row = bm + wm * 64 + fm * 16 + (lane >> 4) * 4 + j;
                C[(size_t)row * KLEN + col] = acc[fm][fn][j] * INV_SCALE + addv;
            }
        }
}

// ---------------------------------------------------------------------------
// 64x64 split-bf16 MFMA NT core (round-12 verified) — kept for out-proj
// ---------------------------------------------------------------------------

DEV_INLINE void mfma_nt_core(const short* __restrict__ Ah, const short* __restrict__ Al, int lda,
                             const short* __restrict__ Bh, const short* __restrict__ Bl, int ldb,
                             int K, int bm, int bn, f32x4 (&acc)[2][2])
{
    __shared__ __align__(16) short AsH[4][4][16][8];
    __shared__ __align__(16) short AsL[4][4][16][8];
    __shared__ __align__(16) short BsH[4][4][16][8];
    __shared__ __align__(16) short BsL[4][4][16][8];
    const int tid  = threadIdx.x;
    const int lane = tid & 63;
    const int w    = tid >> 6;
    const int wm   = w >> 1, wn = w & 1;
    const int r    = tid >> 2;
    const int kg   = tid & 3;
    const int rb   = r >> 4, rr = r & 15;
    const int lkg  = lane >> 4, lrr = lane & 15;

    for (int k0 = 0; k0 < K; k0 += 32) {
        const bf16x8 avh = *(const bf16x8*)(Ah + (size_t)(bm + r) * lda + k0 + kg * 8);
        const bf16x8 avl = *(const bf16x8*)(Al + (size_t)(bm + r) * lda + k0 + kg * 8);
        const bf16x8 bvh = *(const bf16x8*)(Bh + (size_t)(bn + r) * ldb + k0 + kg * 8);
        const bf16x8 bvl = *(const bf16x8*)(Bl + (size_t)(bn + r) * ldb + k0 + kg * 8);
        __syncthreads();
        *(bf16x8*)&AsH[rb][kg][rr][0] = avh;
        *(bf16x8*)&AsL[rb][kg][rr][0] = avl;
        *(bf16x8*)&BsH[rb][kg][rr][0] = bvh;
        *(bf16x8*)&BsL[rb][kg][rr][0] = bvl;
        __syncthreads();
#pragma unroll
        for (int fm = 0; fm < 2; ++fm) {
            const bf16x8 ah = *(const bf16x8*)&AsH[wm * 2 + fm][lkg][lrr][0];
            const bf16x8 al = *(const bf16x8*)&AsL[wm * 2 + fm][lkg][lrr][0];
#pragma unroll
            for (int fn = 0; fn < 2; ++fn) {
                const bf16x8 bh = *(const bf16x8*)&BsH[wn * 2 + fn][lkg][lrr][0];
                const bf16x8 bl = *(const bf16x8*)&BsL[wn * 2 + fn][lkg][lrr][0];
                acc[fm][fn] = __builtin_amdgcn_mfma_f32_16x16x32_bf16(ah, bh, acc[fm][fn], 0, 0, 0);
                acc[fm][fn] = __builtin_amdgcn_mfma_f32_16x16x32_bf16(ah, bl, acc[fm][fn], 0, 0, 0);
                acc[fm][fn] = __builtin_amdgcn_mfma_f32_16x16x32_bf16(al, bh, acc[fm][fn], 0, 0, 0);
            }
        }
    }
}

__global__ __launch_bounds__(256) void mfma_nt_f32_kernel(
    const short* __restrict__ Ah, const short* __restrict__ Al, int lda,
    const short* __restrict__ Bh, const short* __restrict__ Bl, int ldb,
    float* __restrict__ C, int ldc, int K,
    const float* __restrict__ bias)
{
    f32x4 acc[2][2] = {};
    const int bm = blockIdx.x * 64, bn = blockIdx.y * 64;
    mfma_nt_core(Ah, Al, lda, Bh, Bl, ldb, K, bm, bn, acc);
    const int lane = threadIdx.x & 63;
    const int w = threadIdx.x >> 6;
    const int wm = w >> 1, wn = w & 1;
#pragma unroll
    for (int fm = 0; fm < 2; ++fm)
#pragma unroll
        for (int fn = 0; fn < 2; ++fn) {
            const int col = bn + wn * 32 + fn * 16 + (lane & 15);
            const float bvv = bias ? bias[col] : 0.0f;
#pragma unroll
            for (int j = 0; j < 4; ++j) {
                const int row = bm + wm * 32 + fm * 16 + (lane >> 4) * 4 + j;
                C[(size_t)row * ldc + col] = acc[fm][fn][j] + bvv;
            }
        }
}

// ---------------------------------------------------------------------------
// row transforms (round-8 verified)
// ---------------------------------------------------------------------------

__global__ __launch_bounds__(256) void ma_row_kernel(float* __restrict__ PCP,
                                                     float* __restrict__ ICP)
{
    const size_t row = blockIdx.x;
    float* pe = PCP + row * KLEN;
    float* pi = ICP + row * KLEN;
    const int tid = threadIdx.x;
    const int lane = tid & 63, wid = tid >> 6;

    const float4 ev = *(const float4*)(pe + tid * 4);
    float e[4] = {ev.x, ev.y, ev.z, ev.w};
    float p[4], l[4], s[4];
    float run = 0.0f;
#pragma unroll
    for (int j = 0; j < 4; ++j) {
        p[j] = 1.0f / (1.0f + expf(-e[j]));
        float om = 1.0f - p[j];
        om = fminf(fmaxf(om, EPS), 1.0f);
        l[j] = logf(om);
        run += l[j];
        s[j] = run;
    }
    const float t = run;
    float v = t;
#pragma unroll
    for (int off = 1; off < 64; off <<= 1) {
        const float u = __shfl_up(v, off);
        if (lane >= off) v += u;
    }
    __shared__ float wsum[4];
    if (lane == 63) wsum[wid] = v;
    __syncthreads();
    float base = v - t;
    for (int w = 0; w < wid; ++w) base += wsum[w];

    float4 po, io;
    float* pp = (float*)&po;
    float* ip = (float*)&io;
#pragma unroll
    for (int j = 0; j < 4; ++j) {
        const float cum = base + s[j];
        const float cp  = expf(cum - l[j]);
        pp[j] = p[j] * cp;
        ip[j] = 1.0f / fmaxf(cp, EPS);
    }
    *(float4*)(pe + tid * 4) = po;
    *(float4*)(pi + tid * 4) = io;
}

__global__ __launch_bounds__(256) void ca_row_kernel(float* __restrict__ SE,
                                                     float* __restrict__ DEN)
{
    const size_t row = blockIdx.x;
    float* ps = SE + row * KLEN;
    float* pd = DEN + row * KLEN;
    const int tid = threadIdx.x;
    const int lane = tid & 63, wid = tid >> 6;

    const float4 ev = *(const float4*)(ps + tid * 4);
    float e[4] = {ev.x, ev.y, ev.z, ev.w};
    float m = fmaxf(fmaxf(e[0], e[1]), fmaxf(e[2], e[3]));
#pragma unroll
    for (int off = 32; off >= 1; off >>= 1)
        m = fmaxf(m, __shfl_xor(m, off));
    __shared__ float wmax[4];
    if (lane == 0) wmax[wid] = m;
    __syncthreads();
    m = fmaxf(fmaxf(wmax[0], wmax[1]), fmaxf(wmax[2], wmax[3]));

    __shared__ float sh[KLEN + 3];
    if (tid < 3) sh[tid] = 0.0f;
    float se[4];
#pragma unroll
    for (int j = 0; j < 4; ++j) {
        se[j] = fmaxf(expf(e[j] - m), 1e-5f);
        sh[3 + tid * 4 + j] = se[j];
    }
    __syncthreads();
    float4 so, do_;
    float* sp = (float*)&so;
    float* dp = (float*)&do_;
#pragma unroll
    for (int j = 0; j < 4; ++j) {
        const int k = tid * 4 + j;
        sp[j] = se[j];
        dp[j] = sh[3 + k] + sh[2 + k] + sh[1 + k] + sh[k];
    }
    *(float4*)(ps + tid * 4) = so;
    *(float4*)(pd + tid * 4) = do_;
}

// ---------------------------------------------------------------------------
// alpha recurrence (ROUND-8 VERSION, verified): single wave per (b,h_ma),
// DPP wave scan, 8-deep LDS ring via global_load_lds, counted vmcnt.
// ---------------------------------------------------------------------------

template<int CTRL, int ROW_MASK>
DEV_INLINE float dpp_add(float x) {
    int t = __builtin_amdgcn_update_dpp(0, __float_as_int(x), CTRL, ROW_MASK, 0xf, true);
    return x + __int_as_float(t);
}

DEV_INLINE float wave64_incl_scan(float x) {
    x = dpp_add<0x111, 0xf>(x);
    x = dpp_add<0x112, 0xf>(x);
    x = dpp_add<0x114, 0xf>(x);
    x = dpp_add<0x118, 0xf>(x);
    x = dpp_add<0x142, 0xa>(x);
    x = dpp_add<0x143, 0xc>(x);
    return x;
}

typedef __attribute__((address_space(3))) void lv_t;
typedef __attribute__((address_space(1))) const void gv_t;

DEV_INLINE void dma16(const float* g, float* l) {
    __builtin_amdgcn_global_load_lds((gv_t*)g, (lv_t*)l, 16, 0, 0);
}

template<int N> DEV_INLINE void vwait() {
    asm volatile("s_waitcnt vmcnt(%0)" :: "i"(N) : "memory");
    __builtin_amdgcn_sched_barrier(0);
}

DEV_INLINE void alpha_step(const f32x4& P0, const f32x4& P1,
                           const f32x4& P2, const f32x4& P3,
                           const f32x4& I0, const f32x4& I1,
                           const f32x4& I2, const f32x4& I3,
                           float (&a)[16])
{
    float pc[16], ic[16];
    *(f32x4*)&pc[0] = P0; *(f32x4*)&pc[4] = P1;
    *(f32x4*)&pc[8] = P2; *(f32x4*)&pc[12] = P3;
    *(f32x4*)&ic[0] = I0; *(f32x4*)&ic[4] = I1;
    *(f32x4*)&ic[8] = I2; *(f32x4*)&ic[12] = I3;

    float t[16];
#pragma unroll
    for (int j = 0; j < 16; ++j) t[j] = a[j] * ic[j];

    float u1[8], u2[4];
#pragma unroll
    for (int j = 0; j < 8; ++j) u1[j] = t[2 * j] + t[2 * j + 1];
#pragma unroll
    for (int j = 0; j < 4; ++j) u2[j] = u1[2 * j] + u1[2 * j + 1];
    const float tot = (u2[0] + u2[1]) + (u2[2] + u2[3]);

    const float incl = wave64_incl_scan(tot);
    const float excl = incl - tot;

    float s = 0.0f;
#pragma unroll
    for (int j = 0; j < 16; ++j) {
        s += t[j];
        a[j] = pc[j] * (excl + s);
    }
}

#define DMA_ROW(b, prow, irow)                        \
    dma16((prow) + 0,  &ring[b][0][0]);               \
    dma16((prow) + 4,  &ring[b][0][256]);             \
    dma16((prow) + 8,  &ring[b][0][512]);             \
    dma16((prow) + 12, &ring[b][0][768]);             \
    dma16((irow) + 0,  &ring[b][1][0]);               \
    dma16((irow) + 4,  &ring[b][1][256]);             \
    dma16((irow) + 8,  &ring[b][1][512]);             \
    dma16((irow) + 12, &ring[b][1][768]);

#define READ_ROW(b, G)                                   \
    p##G##0 = *(const f32x4*)&ring[b][0][0   + l4];      \
    p##G##1 = *(const f32x4*)&ring[b][0][256 + l4];      \
    p##G##2 = *(const f32x4*)&ring[b][0][512 + l4];      \
    p##G##3 = *(const f32x4*)&ring[b][0][768 + l4];      \
    i##G##0 = *(const f32x4*)&ring[b][1][0   + l4];      \
    i##G##1 = *(const f32x4*)&ring[b][1][256 + l4];      \
    i##G##2 = *(const f32x4*)&ring[b][1][512 + l4];      \
    i##G##3 = *(const f32x4*)&ring[b][1][768 + l4];

#define STEP(WAITN, BUFC, BUFN, DO_READ, DO_DMA, CG, NG)              \
    {                                                                 \
        vwait<WAITN>();                                               \
        if (DO_READ) { READ_ROW(BUFN, NG) }                           \
        alpha_step(p##CG##0, p##CG##1, p##CG##2, p##CG##3,            \
                   i##CG##0, i##CG##1, i##CG##2, i##CG##3, a);        \
        *(f32x4*)(st + 0)  = *(const f32x4*)&a[0];                    \
        *(f32x4*)(st + 4)  = *(const f32x4*)&a[4];                    \
        *(f32x4*)(st + 8)  = *(const f32x4*)&a[8];                    \
        *(f32x4*)(st + 12) = *(const f32x4*)&a[12];                   \
        st += KLEN;                                                   \
        if (DO_DMA) {                                                 \
            __builtin_amdgcn_sched_barrier(0);                        \
            DMA_ROW(BUFC, np, ni)                                     \
            np += KLEN; ni += KLEN;                                   \
        }                                                             \
    }

__global__ __launch_bounds__(64) void alpha_kernel(float* __restrict__ PCP,
                                                   const float* __restrict__ ICP)
{
    __shared__ float ring[8][2][1024];   // 64 KB

    const int z = blockIdx.x;
    float* base = PCP + (size_t)z * QLEN * KLEN;
    const float* ibase = ICP + (size_t)z * QLEN * KLEN;
    const int lane = threadIdx.x;
    const int col = lane * 16;
    const int l4 = lane * 4;

    {
        const float* pp = base + col;
        const float* ip = ibase + col;
        DMA_ROW(0, pp, ip) pp += KLEN; ip += KLEN;
        DMA_ROW(1, pp, ip) pp += KLEN; ip += KLEN;
        DMA_ROW(2, pp, ip) pp += KLEN; ip += KLEN;
        DMA_ROW(3, pp, ip) pp += KLEN; ip += KLEN;
        DMA_ROW(4, pp, ip) pp += KLEN; ip += KLEN;
        DMA_ROW(5, pp, ip) pp += KLEN; ip += KLEN;
        DMA_ROW(6, pp, ip) pp += KLEN; ip += KLEN;
        DMA_ROW(7, pp, ip)
    }

    f32x4 pA0, pA1, pA2, pA3, iA0, iA1, iA2, iA3;
    f32x4 pB0, pB1, pB2, pB3, iB0, iB1, iB2, iB3;

    vwait<56>();
    READ_ROW(0, A)

    float a[16];
#pragma unroll
    for (int j = 0; j < 16; ++j) a[j] = 0.0f;
    if (lane == 0) a[0] = 1.0f;

    float* st = base + col;
    const float* np = base + (size_t)8 * KLEN + col;
    const float* ni = ibase + (size_t)8 * KLEN + col;

    for (int it = 0; it < 63; ++it) {
        STEP(48, 0, 1, true, true, A, B)
        STEP(48, 1, 2, true, true, B, A)
        STEP(48, 2, 3, true, true, A, B)
        STEP(48, 3, 4, true, true, B, A)
        STEP(48, 4, 5, true, true, A, B)
        STEP(48, 5, 6, true, true, B, A)
        STEP(48, 6, 7, true, true, A, B)
        STEP(48, 7, 0, true, true, B, A)
    }

    STEP(48, 0, 1, true, false, A, B)
    STEP(40, 1, 2, true, false, B, A)
    STEP(32, 2, 3, true, false, A, B)
    STEP(24, 3, 4, true, false, B, A)
    STEP(16, 4, 5, true, false, A, B)
    STEP(8,  5, 6, true, false, B, A)
    STEP(0,  6, 7, true, false, A, B)
    STEP(0,  7, 0, false, false, B, A)
}

// ---------------------------------------------------------------------------
// fused beta+cv: V read as bf16 pair from the concat K-projection output.
// ---------------------------------------------------------------------------

__global__ __launch_bounds__(256) void fused_cv_kernel(
    const float* __restrict__ ALPHA, const float* __restrict__ SE,
    const float* __restrict__ DEN,
    const short* __restrict__ VPh, const short* __restrict__ VPl, int ldv,
    short* __restrict__ CVh, short* __restrict__ CVl)
{
    const int z = blockIdx.y;          // b*8 + hma*2 + hca
    const int b = z >> 3;
    const int h = z & 7;
    const int hma = h >> 1;
    const int hca = h & 1;
    const int bm = blockIdx.x * 64;

    const float* a_base  = ALPHA + ((size_t)b * H_MA + hma) * QLEN * KLEN;
    const float* se_base = SE  + ((size_t)b * H_CA + hca) * QLEN * KLEN;
    const float* dn_base = DEN + ((size_t)b * H_CA + hca) * QLEN * KLEN;
    const short* vh_base = VPh + (size_t)b * KLEN * ldv + 1024 + h * 64;
    const short* vl_base = VPl + (size_t)b * KLEN * ldv + 1024 + h * 64;
    short* Ch = CVh + (size_t)b * QLEN * DIM + h * 64;
    short* Cl = CVl + (size_t)b * QLEN * DIM + h * 64;

    __shared__ float As[16][68];
    __shared__ float Bs[16][68];
    const int tid  = threadIdx.x;
    const int tm   = (tid >> 4) << 2;
    const int tn   = (tid & 15) << 2;
    const int arow = tid >> 2;
    const int acol = (tid & 3) << 2;
    const int brow = tid >> 4;
    const int bcol = (tid & 15) << 2;
    float acc[4][4] = {};

    for (int k0 = 0; k0 < KLEN; k0 += 16) {
        const int ka = k0 + acol;
        const size_t roff = (size_t)(bm + arow) * KLEN;
        const f32x4 sev = *(const f32x4*)(se_base + roff + ka);
        const f32x4 al0 = *(const f32x4*)(a_base + roff + ka);
        const f32x4 dn0 = *(const f32x4*)(dn_base + roff + ka);
        f32x4 al1 = {0.0f, 0.0f, 0.0f, 0.0f};
        f32x4 dn1 = {1.0f, 1.0f, 1.0f, 1.0f};
        if (ka + 4 < KLEN) {
            al1 = *(const f32x4*)(a_base + roff + ka + 4);
            dn1 = *(const f32x4*)(dn_base + roff + ka + 4);
        }
        float ad[7];
#pragma unroll
        for (int j = 0; j < 4; ++j) ad[j] = al0[j] / dn0[j];
#pragma unroll
        for (int j = 0; j < 3; ++j) ad[4 + j] = al1[j] / dn1[j];
        const s16x4 vh4 = *(const s16x4*)(vh_base + (size_t)(k0 + brow) * ldv + bcol);
        const s16x4 vl4 = *(const s16x4*)(vl_base + (size_t)(k0 + brow) * ldv + bcol);
        __syncthreads();
        As[acol + 0][arow] = sev[0] * (ad[0] + ad[1] + ad[2] + ad[3]);
        As[acol + 1][arow] = sev[1] * (ad[1] + ad[2] + ad[3] + ad[4]);
        As[acol + 2][arow] = sev[2] * (ad[2] + ad[3] + ad[4] + ad[5]);
        As[acol + 3][arow] = sev[3] * (ad[3] + ad[4] + ad[5] + ad[6]);
#pragma unroll
        for (int j = 0; j < 4; ++j)
            Bs[brow][bcol + j] = bf2f(vh4[j]) + bf2f(vl4[j]);
        __syncthreads();
#pragma unroll
        for (int kk = 0; kk < 16; ++kk) {
            const float4 av = *(const float4*)&As[kk][tm];
            const float4 bw = *(const float4*)&Bs[kk][tn];
            const float ar[4] = {av.x, av.y, av.z, av.w};
            const float br[4] = {bw.x, bw.y, bw.z, bw.w};
#pragma unroll
            for (int i = 0; i < 4; ++i)
#pragma unroll
                for (int j = 0; j < 4; ++j)
                    acc[i][j] = fmaf(ar[i], br[j], acc[i][j]);
        }
    }
#pragma unroll
    for (int i = 0; i < 4; ++i) {
        s16x4 oh, ol;
#pragma unroll
        for (int j = 0; j < 4; ++j) {
            short hh, ll;
            split2(acc[i][j], hh, ll);
            oh[j] = hh; ol[j] = ll;
        }
        const size_t ro = (size_t)(bm + tm + i) * DIM + tn;
        *(s16x4*)(Ch + ro) = oh;
        *(s16x4*)(Cl + ro) = ol;
    }
}

// ---------------------------------------------------------------------------

extern "C" void kernel_launch(void* const* d_in, const int* in_sizes, int n_in,
                              void* d_out, int out_size, void* d_ws, size_t ws_size,
                              hipStream_t stream)
{
    (void)in_sizes; (void)n_in; (void)out_size; (void)ws_size;
    const float* key_t = (const float*)d_in[0];
    const float* query = (const float*)d_in[1];
    const float* wk_ma = (const float*)d_in[2];
    const float* bk_ma = (const float*)d_in[3];
    const float* wq_ma = (const float*)d_in[4];
    const float* bq_ma = (const float*)d_in[5];
    const float* r     = (const float*)d_in[6];
    const float* wk_ca = (const float*)d_in[7];
    const float* bk_ca = (const float*)d_in[8];
    const float* wq_ca = (const float*)d_in[9];
    const float* bq_ca = (const float*)d_in[10];
    const float* wv    = (const float*)d_in[11];
    const float* bv    = (const float*)d_in[12];
    const float* wo    = (const float*)d_in[13];
    const float* bo    = (const float*)d_in[14];
    float* out = (float*)d_out;

    // ---- workspace layout: 146 MiB total
    char* w8 = (char*)d_ws;
    size_t off = 0;
    auto take = [&](size_t n) { char* p = w8 + off; off += n; return p; };
    float* PCP = (float*)take(32ull << 20);
    float* ICP = (float*)take(32ull << 20);
    float* SE  = (float*)take(16ull << 20);
    float* DEN = (float*)take(16ull << 20);
    char* keyrg = take(8ull << 20);              // keyh(4)+keyl(4); CV* overlay
    short* keyh = (short*)keyrg;
    short* keyl = (short*)(keyrg + (4ull << 20));
    short* CVh  = (short*)keyrg;                 // 2 MiB (dead key splits)
    short* CVl  = (short*)(keyrg + (2ull << 20));
    short* qh = (short*)take(2ull << 20);
    short* ql = (short*)take(2ull << 20);
    short* WTkh = (short*)take((size_t)1536 * 512 * 2);
    short* WTkl = (short*)take((size_t)1536 * 512 * 2);
    short* WTqh = (short*)take((size_t)1024 * 512 * 2);
    short* WTql = (short*)take((size_t)1024 * 512 * 2);
    short* WToh = (short*)take((size_t)512 * 512 * 2);
    short* WTol = (short*)take((size_t)512 * 512 * 2);
    short* KPh = (short*)take((size_t)4096 * 1536 * 2);
    short* KPl = (short*)take((size_t)4096 * 1536 * 2);
    short* QPh = (short*)take((size_t)2048 * 1024 * 2);
    short* QPl = (short*)take((size_t)2048 * 1024 * 2);

    const dim3 blk(256);
    const size_t KEL = (size_t)B_ * KLEN * DIM;  // key elements
    const size_t QEL = (size_t)B_ * QLEN * DIM;

    // 1) input/weight conversions
    rowsplit_kernel<<<dim3((int)(KEL / 4 / 256)), blk, 0, stream>>>(key_t, keyh, keyl, (int)(KEL / 4));
    rowsplit_kernel<<<dim3((int)(QEL / 4 / 256)), blk, 0, stream>>>(query, qh, ql, (int)(QEL / 4));
    transsplit_kernel<<<dim3(8, 8), blk, 0, stream>>>(wk_ma, WTkh, WTkl);
    transsplit_kernel<<<dim3(8, 8), blk, 0, stream>>>(wk_ca, WTkh + 512 * 512, WTkl + 512 * 512);
    transsplit_kernel<<<dim3(8, 8), blk, 0, stream>>>(wv, WTkh + 1024 * 512, WTkl + 1024 * 512);
    transsplit_kernel<<<dim3(8, 8), blk, 0, stream>>>(wq_ma, WTqh, WTql);
    transsplit_kernel<<<dim3(8, 8), blk, 0, stream>>>(wq_ca, WTqh + 512 * 512, WTql + 512 * 512);
    transsplit_kernel<<<dim3(8, 8), blk, 0, stream>>>(wo, WToh, WTol);

    // 2) fused projections (128^2 MFMA tiles)
    proj128_kernel<<<dim3(B_ * KLEN / 128, 1536 / 128), blk, 0, stream>>>(
        keyh, keyl, DIM, WTkh, WTkl, DIM, KPh, KPl, 1536, DIM, bk_ma, bk_ca, bv);
    proj128_kernel<<<dim3(B_ * QLEN / 128, 1024 / 128), blk, 0, stream>>>(
        qh, ql, DIM, WTqh, WTql, DIM, QPh, QPl, 1024, DIM, bq_ma, bq_ca, bq_ca);

    // 3) energies (128^2 MFMA tiles)
    energy128_kernel<<<dim3(QLEN / 128, KLEN / 128, B_ * H_MA), blk, 0, stream>>>(
        QPh, QPl, 1024, 0, KPh, KPl, 1536, 0, PCP, H_MA, 128, r);
    energy128_kernel<<<dim3(QLEN / 128, KLEN / 128, B_ * H_CA), blk, 0, stream>>>(
        QPh, QPl, 1024, 512, KPh, KPl, 1536, 512, SE, H_CA, 256, nullptr);

    // 4) row transforms
    ma_row_kernel<<<dim3(B_ * H_MA * QLEN), blk, 0, stream>>>(PCP, ICP);
    ca_row_kernel<<<dim3(B_ * H_CA * QLEN), blk, 0, stream>>>(SE, DEN);

    // 5) monotonic alignment recurrence
    alpha_kernel<<<dim3(B_ * H_MA), dim3(64), 0, stream>>>(PCP, ICP);

    // 6) fused beta+cv (CV emitted as bf16 pair; overlays dead key splits)
    fused_cv_kernel<<<dim3(QLEN / 64, B_ * H_MA * H_CA), blk, 0, stream>>>(
        PCP, SE, DEN, KPh, KPl, 1536, CVh, CVl);

    // 7) output projection (64^2 MFMA, 256 blocks)
    mfma_nt_f32_kernel<<<dim3(B_ * QLEN / 64, DIM / 64), blk, 0, stream>>>(
        CVh, CVl, DIM, WToh, WTol, DIM, out, DIM, DIM, bo);
}